// Round 6
// baseline (350.356 us; speedup 1.0000x reference)
//
#include <hip/hip_runtime.h>
#include <math.h>

constexpr int kT = 12;
constexpr float kNeg = 0.2f;
constexpr float kEps = 1e-5f;
constexpr float kLog2e = 1.44269504088896f;

typedef __attribute__((ext_vector_type(8))) short bf16x8;
typedef __attribute__((ext_vector_type(4))) float f32x4;

__device__ __forceinline__ short f2bf(float f) {
  union { float f; unsigned u; } v;
  v.f = f;
  return (short)((v.u + 0x7fffu + ((v.u >> 16) & 1u)) >> 16);
}
__device__ __forceinline__ unsigned pack2(float a, float b) {
  return (unsigned)(unsigned short)f2bf(a) | ((unsigned)(unsigned short)f2bf(b) << 16);
}

__device__ __forceinline__ float wave_reduce_sum(float v) {
#pragma unroll
  for (int o = 32; o > 0; o >>= 1) v += __shfl_xor(v, o);
  return v;
}

// ---------------------------------------------------------------------------
// bn_stats + one-time MFMA-fragment pre-pack (blocks N..N+3).
// Frag buffers hold A-operand fragments in [fi][lane] order so kernels stage
// them with coalesced dwordx4 loads.
// ---------------------------------------------------------------------------
__global__ void bnprep_kernel(const float* __restrict__ x, const float* __restrict__ g,
                              const float* __restrict__ b, float* __restrict__ scale,
                              float* __restrict__ shift, const float* __restrict__ fw1,
                              const float* __restrict__ fw2, const float* __restrict__ zW1,
                              const float* __restrict__ zW2, bf16x8* __restrict__ fw1f,
                              bf16x8* __restrict__ fw2f, bf16x8* __restrict__ zw1f,
                              bf16x8* __restrict__ zw2f, int N) {
  int blk = blockIdx.x;
  int lane = threadIdx.x & 63, wid = threadIdx.x >> 6;
  if (blk >= N) {
    int which = blk - N;
    int m = lane & 15, q = lane >> 4;
    if (which == 0) {
      for (int fi = wid; fi < 16; fi += 4) {
        int mt = fi >> 1, kc = fi & 1;
        bf16x8 v;
#pragma unroll
        for (int j = 0; j < 8; j++) v[j] = f2bf(fw1[(kc * 32 + q * 8 + j) * 128 + mt * 16 + m]);
        fw1f[fi * 64 + lane] = v;
      }
    } else if (which == 1) {
      for (int fi = wid; fi < 16; fi += 4) {
        int mt2 = fi >> 2, kc2 = fi & 3;
        bf16x8 u;
#pragma unroll
        for (int j = 0; j < 8; j++) u[j] = f2bf(fw2[(kc2 * 32 + q * 8 + j) * 64 + mt2 * 16 + m]);
        fw2f[fi * 64 + lane] = u;
      }
    } else if (which == 2) {
      for (int fi = wid; fi < 8; fi += 4) {
        int mt = fi >> 1, kc = fi & 1;
        bf16x8 v;
#pragma unroll
        for (int j = 0; j < 8; j++) v[j] = f2bf(zW1[(kc * 32 + q * 8 + j) * 64 + mt * 16 + m]);
        zw1f[fi * 64 + lane] = v;
      }
    } else {
      for (int fi = wid; fi < 8; fi += 4) {
        int mt = fi >> 1, kc = fi & 1;
        bf16x8 v;
#pragma unroll
        for (int j = 0; j < 8; j++) v[j] = f2bf(zW2[(kc * 32 + q * 8 + j) * 64 + mt * 16 + m]);
        zw2f[fi * 64 + lane] = v;
      }
    }
    return;
  }
  int n = blk;
  const float* xr = x + (size_t)n * (kT * 64);
  float s = 0.f, s2 = 0.f;
  for (int i = threadIdx.x; i < kT * 64; i += blockDim.x) {
    float v = xr[i];
    s += v;
    s2 += v * v;
  }
  s = wave_reduce_sum(s);
  s2 = wave_reduce_sum(s2);
  __shared__ float ls[4], ls2[4];
  if (lane == 0) { ls[wid] = s; ls2[wid] = s2; }
  __syncthreads();
  if (threadIdx.x == 0) {
    float ts = 0.f, ts2 = 0.f;
    for (int i = 0; i < 4; i++) { ts += ls[i]; ts2 += ls2[i]; }
    const float inv = 1.f / (kT * 64);
    float mean = ts * inv;
    float var = ts2 * inv - mean * mean;
    float sc = rsqrtf(var + kEps) * g[n];
    scale[n] = sc;
    shift[n] = b[n] - mean * sc;
  }
}

// fused degree count for both relations
__global__ void deg_kernel(const int* __restrict__ dst1, const int* __restrict__ dst2,
                           int* __restrict__ deg1, int* __restrict__ deg2, int E1, int E2) {
  int i = blockIdx.x * blockDim.x + threadIdx.x;
  if (i < E1) atomicAdd(&deg1[dst1[i]], 1);
  else if (i < E1 + E2) atomicAdd(&deg2[dst2[i - E1]], 1);
}

// two single-block scans (blockIdx 0 -> rel1, 1 -> rel2), shfl wave-scans
__global__ void scan_kernel(const int* __restrict__ deg1, int* __restrict__ off1,
                            const int* __restrict__ deg2, int* __restrict__ off2, int N) {
  const int* deg = blockIdx.x ? deg2 : deg1;
  int* off = blockIdx.x ? off2 : off1;
  __shared__ int wsum[16];
  __shared__ int carry;
  int tid = threadIdx.x, lane = tid & 63, wv = tid >> 6;
  if (tid == 0) { carry = 0; off[0] = 0; }
  __syncthreads();
  for (int base = 0; base < N; base += 1024) {
    int i = base + tid;
    int incl = (i < N) ? deg[i] : 0;
#pragma unroll
    for (int o = 1; o < 64; o <<= 1) {
      int y = __shfl_up(incl, o);
      if (lane >= o) incl += y;
    }
    if (lane == 63) wsum[wv] = incl;
    __syncthreads();
    if (tid < 16) {
      int p = wsum[tid];
#pragma unroll
      for (int o = 1; o < 16; o <<= 1) {
        int y = __shfl_up(p, o);
        if (tid >= o) p += y;
      }
      wsum[tid] = p;
    }
    __syncthreads();
    int prefix = carry + (wv > 0 ? wsum[wv - 1] : 0);
    if (i < N) off[i + 1] = prefix + incl;
    int total = carry + wsum[15];
    __syncthreads();
    if (tid == 0) carry = total;
    __syncthreads();
  }
}

// fused CSR fill; stores src*kT (z-row base)
__global__ void fill_kernel(const int* __restrict__ src1, const int* __restrict__ dst1,
                            const int* __restrict__ off1, int* __restrict__ cur1,
                            int* __restrict__ scsr1, const int* __restrict__ src2,
                            const int* __restrict__ dst2, const int* __restrict__ off2,
                            int* __restrict__ cur2, int* __restrict__ scsr2, int E1, int E2) {
  int i = blockIdx.x * blockDim.x + threadIdx.x;
  if (i < E1) {
    int d = dst1[i];
    int p = atomicAdd(&cur1[d], 1);
    scsr1[off1[d] + p] = src1[i] * kT;
  } else if (i < E1 + E2) {
    int k = i - E1;
    int d = dst2[k];
    int p = atomicAdd(&cur2[d], 1);
    scsr2[off2[d] + p] = src2[k] * kT;
  }
}

// ---------------------------------------------------------------------------
// MFMA zel: frag staging now coalesced from prepacked buffers.
// ---------------------------------------------------------------------------
__global__ __launch_bounds__(256) void zel_kernel(
    const float* __restrict__ x, const float* __restrict__ scale,
    const float* __restrict__ shift, const bf16x8* __restrict__ zw1f,
    const bf16x8* __restrict__ zw2f, const float* __restrict__ al1,
    const float* __restrict__ ar1, const float* __restrict__ al2,
    const float* __restrict__ ar2, unsigned short* __restrict__ z1,
    unsigned short* __restrict__ z2, float* __restrict__ el1, float* __restrict__ er1,
    float* __restrict__ el2, float* __restrict__ er2, int NT) {
  __shared__ bf16x8 sW1[8][64];
  __shared__ bf16x8 sW2[8][64];
  int lane = threadIdx.x & 63, wid = threadIdx.x >> 6;
  int m = lane & 15, q = lane >> 4;
  for (int fi = wid; fi < 8; fi += 4) {
    sW1[fi][lane] = zw1f[fi * 64 + lane];
    sW2[fi][lane] = zw2f[fi * 64 + lane];
  }
  __syncthreads();
  float al1r[4][4], ar1r[4][4], al2r[4][4], ar2r[4][4];
#pragma unroll
  for (int h = 0; h < 4; h++)
#pragma unroll
    for (int r = 0; r < 4; r++) {
      int f = h * 16 + 4 * q + r;
      al1r[h][r] = al1[f] * kLog2e;
      ar1r[h][r] = ar1[f] * kLog2e;
      al2r[h][r] = al2[f] * kLog2e;
      ar2r[h][r] = ar2[f] * kLog2e;
    }
  int ntile = (NT + 15) / 16;
  for (int tile = blockIdx.x * 4 + wid; tile < ntile; tile += gridDim.x * 4) {
    int r0 = tile * 16;
    int row = r0 + m;
    int rowc = (row < NT) ? row : NT - 1;
    int n = rowc / kT;
    float sc = scale[n], sh = shift[n];
    bf16x8 hf[2];
#pragma unroll
    for (int kc = 0; kc < 2; kc++) {
      float4 p0 = *(const float4*)&x[(size_t)rowc * 64 + kc * 32 + q * 8];
      float4 p1 = *(const float4*)&x[(size_t)rowc * 64 + kc * 32 + q * 8 + 4];
      hf[kc][0] = f2bf(fmaf(p0.x, sc, sh));
      hf[kc][1] = f2bf(fmaf(p0.y, sc, sh));
      hf[kc][2] = f2bf(fmaf(p0.z, sc, sh));
      hf[kc][3] = f2bf(fmaf(p0.w, sc, sh));
      hf[kc][4] = f2bf(fmaf(p1.x, sc, sh));
      hf[kc][5] = f2bf(fmaf(p1.y, sc, sh));
      hf[kc][6] = f2bf(fmaf(p1.z, sc, sh));
      hf[kc][7] = f2bf(fmaf(p1.w, sc, sh));
    }
    f32x4 a1[4], a2[4];
#pragma unroll
    for (int mt = 0; mt < 4; mt++) {
      a1[mt] = (f32x4){0.f, 0.f, 0.f, 0.f};
      a2[mt] = (f32x4){0.f, 0.f, 0.f, 0.f};
    }
#pragma unroll
    for (int kc = 0; kc < 2; kc++)
#pragma unroll
      for (int mt = 0; mt < 4; mt++) {
        a1[mt] = __builtin_amdgcn_mfma_f32_16x16x32_bf16(sW1[mt * 2 + kc][lane], hf[kc],
                                                         a1[mt], 0, 0, 0);
        a2[mt] = __builtin_amdgcn_mfma_f32_16x16x32_bf16(sW2[mt * 2 + kc][lane], hf[kc],
                                                         a2[mt], 0, 0, 0);
      }
    float e1l[4], e1r[4], e2l[4], e2r[4];
#pragma unroll
    for (int h = 0; h < 4; h++) {
      float pl1 = 0.f, pr1 = 0.f, pl2 = 0.f, pr2 = 0.f;
#pragma unroll
      for (int r = 0; r < 4; r++) {
        pl1 = fmaf(a1[h][r], al1r[h][r], pl1);
        pr1 = fmaf(a1[h][r], ar1r[h][r], pr1);
        pl2 = fmaf(a2[h][r], al2r[h][r], pl2);
        pr2 = fmaf(a2[h][r], ar2r[h][r], pr2);
      }
#pragma unroll
      for (int o = 16; o < 64; o <<= 1) {
        pl1 += __shfl_xor(pl1, o);
        pr1 += __shfl_xor(pr1, o);
        pl2 += __shfl_xor(pl2, o);
        pr2 += __shfl_xor(pr2, o);
      }
      e1l[h] = pl1; e1r[h] = pr1; e2l[h] = pl2; e2r[h] = pr2;
    }
    if (row < NT) {
      if (q == 0) {
        *(float4*)&el1[(size_t)row * 4] = make_float4(e1l[0], e1l[1], e1l[2], e1l[3]);
        *(float4*)&er1[(size_t)row * 4] = make_float4(e1r[0], e1r[1], e1r[2], e1r[3]);
        *(float4*)&el2[(size_t)row * 4] = make_float4(e2l[0], e2l[1], e2l[2], e2l[3]);
        *(float4*)&er2[(size_t)row * 4] = make_float4(e2r[0], e2r[1], e2r[2], e2r[3]);
      }
#pragma unroll
      for (int mt = 0; mt < 4; mt++) {
        uint2 u1 = {pack2(a1[mt][0], a1[mt][1]), pack2(a1[mt][2], a1[mt][3])};
        uint2 u2 = {pack2(a2[mt][0], a2[mt][1]), pack2(a2[mt][2], a2[mt][3])};
        *(uint2*)&z1[(size_t)row * 64 + mt * 16 + 4 * q] = u1;
        *(uint2*)&z2[(size_t)row * 64 + mt * 16 + 4 * q] = u2;
      }
    }
  }
}

// ---------------------------------------------------------------------------
// agg: one wave per (node, t-block of 4); hand software-pipelined edge loop
// (next el/z prefetched with clamped index while current is consumed).
// ---------------------------------------------------------------------------
__device__ __forceinline__ void gat_rel(int n, int t, const int* __restrict__ scsr,
                                        const int* __restrict__ off, const float* elp,
                                        float er_h, const unsigned short* zp, float& a0,
                                        float& a1, float& a2, float& a3) {
  int b0 = off[n], b1 = off[n + 1];
  if (b1 <= b0) return;
  float den = 0.f, n0 = 0.f, n1 = 0.f, n2 = 0.f, n3 = 0.f;
  int sb = scsr[b0];
  int srow = sb + t;
  float elv = elp[(size_t)srow * 4];
  uint2 zv = *(const uint2*)(zp + (size_t)srow * 64);
  for (int j = b0; j < b1; j++) {
    int jn = (j + 1 < b1) ? j + 1 : j;
    int sbn = scsr[jn];
    int srown = sbn + t;
    float elvn = elp[(size_t)srown * 4];
    uint2 zvn = *(const uint2*)(zp + (size_t)srown * 64);
    float ev = elv + er_h;
    ev = fmaxf(ev, kNeg * ev);
    float wgt = exp2f(ev);
    den += wgt;
    n0 = fmaf(wgt, __uint_as_float(zv.x << 16), n0);
    n1 = fmaf(wgt, __uint_as_float(zv.x & 0xffff0000u), n1);
    n2 = fmaf(wgt, __uint_as_float(zv.y << 16), n2);
    n3 = fmaf(wgt, __uint_as_float(zv.y & 0xffff0000u), n3);
    elv = elvn;
    zv = zvn;
  }
  float inv = 1.f / den;
  a0 = fmaf(n0, inv, a0);
  a1 = fmaf(n1, inv, a1);
  a2 = fmaf(n2, inv, a2);
  a3 = fmaf(n3, inv, a3);
}

__global__ __launch_bounds__(256) void agg_kernel(
    const float* __restrict__ x, const int* __restrict__ scsr1,
    const int* __restrict__ off1, const float* __restrict__ el1,
    const float* __restrict__ er1, const unsigned short* __restrict__ z1,
    const int* __restrict__ scsr2, const int* __restrict__ off2,
    const float* __restrict__ el2, const float* __restrict__ er2,
    const unsigned short* __restrict__ z2, float* __restrict__ x2,
    float* __restrict__ bn2s, float* __restrict__ bn2q, int N) {
  int wid = threadIdx.x >> 6, lane = threadIdx.x & 63;
  int w = blockIdx.x * 4 + wid;
  if (w >= N * 3) return;
  int n = w / 3;
  int t0 = (w - n * 3) * 4;
  int tl = lane >> 4, cg = lane & 15;
  int t = t0 + tl;
  int row = n * kT + t;
  int h = cg >> 2;
  float a0 = 0.f, a1 = 0.f, a2 = 0.f, a3 = 0.f;
  gat_rel(n, t, scsr1, off1, el1 + h, er1[(size_t)row * 4 + h], z1 + cg * 4, a0, a1, a2, a3);
  gat_rel(n, t, scsr2, off2, el2 + h, er2[(size_t)row * 4 + h], z2 + cg * 4, a0, a1, a2, a3);

  size_t base = (size_t)row * 64 + cg * 4;
  float4 xr = *(const float4*)&x[base];
  float4 o;
  o.x = xr.x + a0;
  o.y = xr.y + a1;
  o.z = xr.z + a2;
  o.w = xr.w + a3;
  *(float4*)&x2[base] = o;
  float s1 = o.x + o.y + o.z + o.w;
  float s2 = o.x * o.x + o.y * o.y + o.z * o.z + o.w * o.w;
  s1 = wave_reduce_sum(s1);
  s2 = wave_reduce_sum(s2);
  if (lane == 0) {
    atomicAdd(&bn2s[n], s1);
    atomicAdd(&bn2q[n], s2);
  }
}

// ---------------------------------------------------------------------------
// MFMA FF: coalesced frag staging, biases in LDS, incremental GEMM2 (low
// VGPR), 4 waves/SIMD target, one tile per wave.
// ---------------------------------------------------------------------------
__global__ __launch_bounds__(256, 4) void ff_kernel(
    const float* __restrict__ x2, const float* __restrict__ bn2s,
    const float* __restrict__ bn2q, const float* __restrict__ bng,
    const float* __restrict__ bnb, const bf16x8* __restrict__ w1f,
    const bf16x8* __restrict__ w2f, const float* __restrict__ b1,
    const float* __restrict__ b2, float* __restrict__ out, int NT) {
  __shared__ bf16x8 sW1[16][64];
  __shared__ bf16x8 sW2[16][64];
  __shared__ float sB1[128];
  __shared__ float sB2[64];
  int lane = threadIdx.x & 63, wid = threadIdx.x >> 6;
  int m = lane & 15, q = lane >> 4;
  {
    int fi0 = wid * 4;
#pragma unroll
    for (int k = 0; k < 4; k++) {
      sW1[fi0 + k][lane] = w1f[(fi0 + k) * 64 + lane];
      sW2[fi0 + k][lane] = w2f[(fi0 + k) * 64 + lane];
    }
    if (threadIdx.x < 128) sB1[threadIdx.x] = b1[threadIdx.x];
    if (threadIdx.x < 64) sB2[threadIdx.x] = b2[threadIdx.x];
  }
  __syncthreads();

  const float inv = 1.f / (kT * 64);
  int ntile = (NT + 15) / 16;
  for (int tile = blockIdx.x * 4 + wid; tile < ntile; tile += gridDim.x * 4) {
    int r0 = tile * 16;
    int row = r0 + m;
    int rowc = (row < NT) ? row : NT - 1;
    int n = rowc / kT;
    float mean = bn2s[n] * inv;
    float var = bn2q[n] * inv - mean * mean;
    float sc = rsqrtf(var + kEps) * bng[n];
    float sh = bnb[n] - mean * sc;

    bf16x8 hf[2];
#pragma unroll
    for (int kc = 0; kc < 2; kc++) {
      const float4 p0 = *(const float4*)&x2[(size_t)rowc * 64 + kc * 32 + q * 8];
      const float4 p1 = *(const float4*)&x2[(size_t)rowc * 64 + kc * 32 + q * 8 + 4];
      hf[kc][0] = f2bf(fmaf(p0.x, sc, sh));
      hf[kc][1] = f2bf(fmaf(p0.y, sc, sh));
      hf[kc][2] = f2bf(fmaf(p0.z, sc, sh));
      hf[kc][3] = f2bf(fmaf(p0.w, sc, sh));
      hf[kc][4] = f2bf(fmaf(p1.x, sc, sh));
      hf[kc][5] = f2bf(fmaf(p1.y, sc, sh));
      hf[kc][6] = f2bf(fmaf(p1.z, sc, sh));
      hf[kc][7] = f2bf(fmaf(p1.w, sc, sh));
    }

    f32x4 acc[8];
#pragma unroll
    for (int mt = 0; mt < 8; mt++) acc[mt] = (f32x4){0.f, 0.f, 0.f, 0.f};
#pragma unroll
    for (int kc = 0; kc < 2; kc++)
#pragma unroll
      for (int mt = 0; mt < 8; mt++)
        acc[mt] = __builtin_amdgcn_mfma_f32_16x16x32_bf16(sW1[mt * 2 + kc][lane], hf[kc],
                                                          acc[mt], 0, 0, 0);

    // incremental GEMM2: per k-chunk, GELU the source pair, shuffle-relayout,
    // MFMA-accumulate. Keeps live register footprint small.
    f32x4 acc2[4];
#pragma unroll
    for (int mt = 0; mt < 4; mt++) acc2[mt] = (f32x4){0.f, 0.f, 0.f, 0.f};
#pragma unroll
    for (int kc = 0; kc < 4; kc++) {
      float4 bb0 = *(const float4*)&sB1[(2 * kc) * 16 + 4 * q];
      float4 bb1 = *(const float4*)&sB1[(2 * kc + 1) * 16 + 4 * q];
      float g0[4], g1[4];
      {
        float u;
        u = acc[2 * kc][0] + bb0.x; g0[0] = 0.5f * u * (1.f + erff(u * 0.70710678118654752f));
        u = acc[2 * kc][1] + bb0.y; g0[1] = 0.5f * u * (1.f + erff(u * 0.70710678118654752f));
        u = acc[2 * kc][2] + bb0.z; g0[2] = 0.5f * u * (1.f + erff(u * 0.70710678118654752f));
        u = acc[2 * kc][3] + bb0.w; g0[3] = 0.5f * u * (1.f + erff(u * 0.70710678118654752f));
        u = acc[2 * kc + 1][0] + bb1.x; g1[0] = 0.5f * u * (1.f + erff(u * 0.70710678118654752f));
        u = acc[2 * kc + 1][1] + bb1.y; g1[1] = 0.5f * u * (1.f + erff(u * 0.70710678118654752f));
        u = acc[2 * kc + 1][2] + bb1.z; g1[2] = 0.5f * u * (1.f + erff(u * 0.70710678118654752f));
        u = acc[2 * kc + 1][3] + bb1.w; g1[3] = 0.5f * u * (1.f + erff(u * 0.70710678118654752f));
      }
      bf16x8 bf;
#pragma unroll
      for (int j = 0; j < 8; j++) {
        int srcq = (2 * q + (j >> 2)) & 3;
        int src = srcq * 16 + m;
        float v0 = __shfl(g0[j & 3], src);
        float v1 = __shfl(g1[j & 3], src);
        bf[j] = f2bf((q >= 2) ? v1 : v0);
      }
#pragma unroll
      for (int mt = 0; mt < 4; mt++)
        acc2[mt] = __builtin_amdgcn_mfma_f32_16x16x32_bf16(sW2[mt * 4 + kc][lane], bf,
                                                           acc2[mt], 0, 0, 0);
    }

    if (row < NT) {
#pragma unroll
      for (int mt = 0; mt < 4; mt++) {
        size_t base = (size_t)row * 64 + mt * 16 + 4 * q;
        float4 xr = *(const float4*)&x2[base];
        float4 bb = *(const float4*)&sB2[mt * 16 + 4 * q];
        float4 o;
        o.x = acc2[mt][0] + bb.x + xr.x;
        o.y = acc2[mt][1] + bb.y + xr.y;
        o.z = acc2[mt][2] + bb.z + xr.z;
        o.w = acc2[mt][3] + bb.w + xr.w;
        *(float4*)&out[base] = o;
      }
    }
  }
}

extern "C" void kernel_launch(void* const* d_in, const int* in_sizes, int n_in,
                              void* d_out, int out_size, void* d_ws, size_t ws_size,
                              hipStream_t stream) {
  const float* x = (const float*)d_in[0];
  const int* src1 = (const int*)d_in[1];
  const int* dst1 = (const int*)d_in[2];
  const int* src2 = (const int*)d_in[3];
  const int* dst2 = (const int*)d_in[4];
  const float* W1 = (const float*)d_in[5];
  const float* al1 = (const float*)d_in[6];
  const float* ar1 = (const float*)d_in[7];
  const float* W2 = (const float*)d_in[8];
  const float* al2 = (const float*)d_in[9];
  const float* ar2 = (const float*)d_in[10];
  const float* g1 = (const float*)d_in[11];
  const float* b1 = (const float*)d_in[12];
  const float* g2 = (const float*)d_in[13];
  const float* b2 = (const float*)d_in[14];
  const float* fw1 = (const float*)d_in[15];
  const float* fb1 = (const float*)d_in[16];
  const float* fw2 = (const float*)d_in[17];
  const float* fb2 = (const float*)d_in[18];

  const int N = in_sizes[11];
  const int E1 = in_sizes[1];
  const int E2 = in_sizes[3];
  const int NT = N * kT;

  char* p = (char*)d_ws;
  auto alloc = [&](size_t bytes) -> char* {
    char* r = p;
    p += (bytes + 255) & ~(size_t)255;
    return r;
  };
  unsigned short* z1 = (unsigned short*)alloc((size_t)NT * 64 * 2);
  unsigned short* z2 = (unsigned short*)alloc((size_t)NT * 64 * 2);
  float* el1 = (float*)alloc((size_t)NT * 4 * 4);
  float* er1 = (float*)alloc((size_t)NT * 4 * 4);
  float* el2 = (float*)alloc((size_t)NT * 4 * 4);
  float* er2 = (float*)alloc((size_t)NT * 4 * 4);
  float* x2 = (float*)alloc((size_t)NT * 64 * 4);
  float* sc1 = (float*)alloc((size_t)N * 4);
  float* sh1 = (float*)alloc((size_t)N * 4);
  int* off1 = (int*)alloc((size_t)(N + 1) * 4);
  int* off2 = (int*)alloc((size_t)(N + 1) * 4);
  int* scsr1 = (int*)alloc((size_t)E1 * 4);
  int* scsr2 = (int*)alloc((size_t)E2 * 4);
  bf16x8* fw1f = (bf16x8*)alloc(16 * 64 * 16);
  bf16x8* fw2f = (bf16x8*)alloc(16 * 64 * 16);
  bf16x8* zw1f = (bf16x8*)alloc(8 * 64 * 16);
  bf16x8* zw2f = (bf16x8*)alloc(8 * 64 * 16);
  char* zero_base = p;
  int* deg1 = (int*)alloc((size_t)N * 4);
  int* cur1 = (int*)alloc((size_t)N * 4);
  int* deg2 = (int*)alloc((size_t)N * 4);
  int* cur2 = (int*)alloc((size_t)N * 4);
  float* bn2s = (float*)alloc((size_t)N * 4);
  float* bn2q = (float*)alloc((size_t)N * 4);
  size_t zero_bytes = (size_t)(p - zero_base);
  hipMemsetAsync(zero_base, 0, zero_bytes, stream);

  bnprep_kernel<<<N + 4, 256, 0, stream>>>(x, g1, b1, sc1, sh1, fw1, fw2, W1, W2, fw1f, fw2f,
                                           zw1f, zw2f, N);
  deg_kernel<<<(E1 + E2 + 255) / 256, 256, 0, stream>>>(dst1, dst2, deg1, deg2, E1, E2);
  scan_kernel<<<2, 1024, 0, stream>>>(deg1, off1, deg2, off2, N);
  fill_kernel<<<(E1 + E2 + 255) / 256, 256, 0, stream>>>(src1, dst1, off1, cur1, scsr1, src2,
                                                         dst2, off2, cur2, scsr2, E1, E2);
  zel_kernel<<<1875, 256, 0, stream>>>(x, sc1, sh1, zw1f, zw2f, al1, ar1, al2, ar2, z1, z2,
                                       el1, er1, el2, er2, NT);
  agg_kernel<<<(N * 3 + 3) / 4, 256, 0, stream>>>(x, scsr1, off1, el1, er1, z1, scsr2, off2,
                                                  el2, er2, z2, x2, bn2s, bn2q, N);
  ff_kernel<<<1875, 256, 0, stream>>>(x2, bn2s, bn2q, g2, b2, fw1f, fw2f, fb1, fb2,
                                      (float*)d_out, NT);
}

// Round 7
// 286.349 us; speedup vs baseline: 1.2235x; 1.2235x over previous
//
#include <hip/hip_runtime.h>
#include <math.h>

constexpr int kT = 12;
constexpr float kNeg = 0.2f;
constexpr float kEps = 1e-5f;
constexpr float kLog2e = 1.44269504088896f;

typedef __attribute__((ext_vector_type(8))) short bf16x8;
typedef __attribute__((ext_vector_type(4))) float f32x4;

__device__ __forceinline__ short f2bf(float f) {
  union { float f; unsigned u; } v;
  v.f = f;
  return (short)((v.u + 0x7fffu + ((v.u >> 16) & 1u)) >> 16);
}
__device__ __forceinline__ unsigned pack2(float a, float b) {
  return (unsigned)(unsigned short)f2bf(a) | ((unsigned)(unsigned short)f2bf(b) << 16);
}

__device__ __forceinline__ float wave_reduce_sum(float v) {
#pragma unroll
  for (int o = 32; o > 0; o >>= 1) v += __shfl_xor(v, o);
  return v;
}

// ---------------------------------------------------------------------------
// bn_stats + one-time MFMA-fragment pre-pack (blocks N..N+3).
// ---------------------------------------------------------------------------
__global__ void bnprep_kernel(const float* __restrict__ x, const float* __restrict__ g,
                              const float* __restrict__ b, float* __restrict__ scale,
                              float* __restrict__ shift, const float* __restrict__ fw1,
                              const float* __restrict__ fw2, const float* __restrict__ zW1,
                              const float* __restrict__ zW2, bf16x8* __restrict__ fw1f,
                              bf16x8* __restrict__ fw2f, bf16x8* __restrict__ zw1f,
                              bf16x8* __restrict__ zw2f, int N) {
  int blk = blockIdx.x;
  int lane = threadIdx.x & 63, wid = threadIdx.x >> 6;
  if (blk >= N) {
    int which = blk - N;
    int m = lane & 15, q = lane >> 4;
    if (which == 0) {
      for (int fi = wid; fi < 16; fi += 4) {
        int mt = fi >> 1, kc = fi & 1;
        bf16x8 v;
#pragma unroll
        for (int j = 0; j < 8; j++) v[j] = f2bf(fw1[(kc * 32 + q * 8 + j) * 128 + mt * 16 + m]);
        fw1f[fi * 64 + lane] = v;
      }
    } else if (which == 1) {
      for (int fi = wid; fi < 16; fi += 4) {
        int mt2 = fi >> 2, kc2 = fi & 3;
        bf16x8 u;
#pragma unroll
        for (int j = 0; j < 8; j++) u[j] = f2bf(fw2[(kc2 * 32 + q * 8 + j) * 64 + mt2 * 16 + m]);
        fw2f[fi * 64 + lane] = u;
      }
    } else if (which == 2) {
      for (int fi = wid; fi < 8; fi += 4) {
        int mt = fi >> 1, kc = fi & 1;
        bf16x8 v;
#pragma unroll
        for (int j = 0; j < 8; j++) v[j] = f2bf(zW1[(kc * 32 + q * 8 + j) * 64 + mt * 16 + m]);
        zw1f[fi * 64 + lane] = v;
      }
    } else {
      for (int fi = wid; fi < 8; fi += 4) {
        int mt = fi >> 1, kc = fi & 1;
        bf16x8 v;
#pragma unroll
        for (int j = 0; j < 8; j++) v[j] = f2bf(zW2[(kc * 32 + q * 8 + j) * 64 + mt * 16 + m]);
        zw2f[fi * 64 + lane] = v;
      }
    }
    return;
  }
  int n = blk;
  const float* xr = x + (size_t)n * (kT * 64);
  float s = 0.f, s2 = 0.f;
  for (int i = threadIdx.x; i < kT * 64; i += blockDim.x) {
    float v = xr[i];
    s += v;
    s2 += v * v;
  }
  s = wave_reduce_sum(s);
  s2 = wave_reduce_sum(s2);
  __shared__ float ls[4], ls2[4];
  if (lane == 0) { ls[wid] = s; ls2[wid] = s2; }
  __syncthreads();
  if (threadIdx.x == 0) {
    float ts = 0.f, ts2 = 0.f;
    for (int i = 0; i < 4; i++) { ts += ls[i]; ts2 += ls2[i]; }
    const float inv = 1.f / (kT * 64);
    float mean = ts * inv;
    float var = ts2 * inv - mean * mean;
    float sc = rsqrtf(var + kEps) * g[n];
    scale[n] = sc;
    shift[n] = b[n] - mean * sc;
  }
}

// fused degree count for both relations
__global__ void deg_kernel(const int* __restrict__ dst1, const int* __restrict__ dst2,
                           int* __restrict__ deg1, int* __restrict__ deg2, int E1, int E2) {
  int i = blockIdx.x * blockDim.x + threadIdx.x;
  if (i < E1) atomicAdd(&deg1[dst1[i]], 1);
  else if (i < E1 + E2) atomicAdd(&deg2[dst2[i - E1]], 1);
}

// two single-block scans (blockIdx 0 -> rel1, 1 -> rel2), shfl wave-scans
__global__ void scan_kernel(const int* __restrict__ deg1, int* __restrict__ off1,
                            const int* __restrict__ deg2, int* __restrict__ off2, int N) {
  const int* deg = blockIdx.x ? deg2 : deg1;
  int* off = blockIdx.x ? off2 : off1;
  __shared__ int wsum[16];
  __shared__ int carry;
  int tid = threadIdx.x, lane = tid & 63, wv = tid >> 6;
  if (tid == 0) { carry = 0; off[0] = 0; }
  __syncthreads();
  for (int base = 0; base < N; base += 1024) {
    int i = base + tid;
    int incl = (i < N) ? deg[i] : 0;
#pragma unroll
    for (int o = 1; o < 64; o <<= 1) {
      int y = __shfl_up(incl, o);
      if (lane >= o) incl += y;
    }
    if (lane == 63) wsum[wv] = incl;
    __syncthreads();
    if (tid < 16) {
      int p = wsum[tid];
#pragma unroll
      for (int o = 1; o < 16; o <<= 1) {
        int y = __shfl_up(p, o);
        if (tid >= o) p += y;
      }
      wsum[tid] = p;
    }
    __syncthreads();
    int prefix = carry + (wv > 0 ? wsum[wv - 1] : 0);
    if (i < N) off[i + 1] = prefix + incl;
    int total = carry + wsum[15];
    __syncthreads();
    if (tid == 0) carry = total;
    __syncthreads();
  }
}

// fused CSR fill; stores src*kT (z-row base)
__global__ void fill_kernel(const int* __restrict__ src1, const int* __restrict__ dst1,
                            const int* __restrict__ off1, int* __restrict__ cur1,
                            int* __restrict__ scsr1, const int* __restrict__ src2,
                            const int* __restrict__ dst2, const int* __restrict__ off2,
                            int* __restrict__ cur2, int* __restrict__ scsr2, int E1, int E2) {
  int i = blockIdx.x * blockDim.x + threadIdx.x;
  if (i < E1) {
    int d = dst1[i];
    int p = atomicAdd(&cur1[d], 1);
    scsr1[off1[d] + p] = src1[i] * kT;
  } else if (i < E1 + E2) {
    int k = i - E1;
    int d = dst2[k];
    int p = atomicAdd(&cur2[d], 1);
    scsr2[off2[d] + p] = src2[k] * kT;
  }
}

// ---------------------------------------------------------------------------
// MFMA zel: frag staging coalesced from prepacked buffers.
// ---------------------------------------------------------------------------
__global__ __launch_bounds__(256) void zel_kernel(
    const float* __restrict__ x, const float* __restrict__ scale,
    const float* __restrict__ shift, const bf16x8* __restrict__ zw1f,
    const bf16x8* __restrict__ zw2f, const float* __restrict__ al1,
    const float* __restrict__ ar1, const float* __restrict__ al2,
    const float* __restrict__ ar2, unsigned short* __restrict__ z1,
    unsigned short* __restrict__ z2, float* __restrict__ el1, float* __restrict__ er1,
    float* __restrict__ el2, float* __restrict__ er2, int NT) {
  __shared__ bf16x8 sW1[8][64];
  __shared__ bf16x8 sW2[8][64];
  int lane = threadIdx.x & 63, wid = threadIdx.x >> 6;
  int m = lane & 15, q = lane >> 4;
  for (int fi = wid; fi < 8; fi += 4) {
    sW1[fi][lane] = zw1f[fi * 64 + lane];
    sW2[fi][lane] = zw2f[fi * 64 + lane];
  }
  __syncthreads();
  float al1r[4][4], ar1r[4][4], al2r[4][4], ar2r[4][4];
#pragma unroll
  for (int h = 0; h < 4; h++)
#pragma unroll
    for (int r = 0; r < 4; r++) {
      int f = h * 16 + 4 * q + r;
      al1r[h][r] = al1[f] * kLog2e;
      ar1r[h][r] = ar1[f] * kLog2e;
      al2r[h][r] = al2[f] * kLog2e;
      ar2r[h][r] = ar2[f] * kLog2e;
    }
  int ntile = (NT + 15) / 16;
  for (int tile = blockIdx.x * 4 + wid; tile < ntile; tile += gridDim.x * 4) {
    int r0 = tile * 16;
    int row = r0 + m;
    int rowc = (row < NT) ? row : NT - 1;
    int n = rowc / kT;
    float sc = scale[n], sh = shift[n];
    bf16x8 hf[2];
#pragma unroll
    for (int kc = 0; kc < 2; kc++) {
      float4 p0 = *(const float4*)&x[(size_t)rowc * 64 + kc * 32 + q * 8];
      float4 p1 = *(const float4*)&x[(size_t)rowc * 64 + kc * 32 + q * 8 + 4];
      hf[kc][0] = f2bf(fmaf(p0.x, sc, sh));
      hf[kc][1] = f2bf(fmaf(p0.y, sc, sh));
      hf[kc][2] = f2bf(fmaf(p0.z, sc, sh));
      hf[kc][3] = f2bf(fmaf(p0.w, sc, sh));
      hf[kc][4] = f2bf(fmaf(p1.x, sc, sh));
      hf[kc][5] = f2bf(fmaf(p1.y, sc, sh));
      hf[kc][6] = f2bf(fmaf(p1.z, sc, sh));
      hf[kc][7] = f2bf(fmaf(p1.w, sc, sh));
    }
    f32x4 a1[4], a2[4];
#pragma unroll
    for (int mt = 0; mt < 4; mt++) {
      a1[mt] = (f32x4){0.f, 0.f, 0.f, 0.f};
      a2[mt] = (f32x4){0.f, 0.f, 0.f, 0.f};
    }
#pragma unroll
    for (int kc = 0; kc < 2; kc++)
#pragma unroll
      for (int mt = 0; mt < 4; mt++) {
        a1[mt] = __builtin_amdgcn_mfma_f32_16x16x32_bf16(sW1[mt * 2 + kc][lane], hf[kc],
                                                         a1[mt], 0, 0, 0);
        a2[mt] = __builtin_amdgcn_mfma_f32_16x16x32_bf16(sW2[mt * 2 + kc][lane], hf[kc],
                                                         a2[mt], 0, 0, 0);
      }
    float e1l[4], e1r[4], e2l[4], e2r[4];
#pragma unroll
    for (int h = 0; h < 4; h++) {
      float pl1 = 0.f, pr1 = 0.f, pl2 = 0.f, pr2 = 0.f;
#pragma unroll
      for (int r = 0; r < 4; r++) {
        pl1 = fmaf(a1[h][r], al1r[h][r], pl1);
        pr1 = fmaf(a1[h][r], ar1r[h][r], pr1);
        pl2 = fmaf(a2[h][r], al2r[h][r], pl2);
        pr2 = fmaf(a2[h][r], ar2r[h][r], pr2);
      }
#pragma unroll
      for (int o = 16; o < 64; o <<= 1) {
        pl1 += __shfl_xor(pl1, o);
        pr1 += __shfl_xor(pr1, o);
        pl2 += __shfl_xor(pl2, o);
        pr2 += __shfl_xor(pr2, o);
      }
      e1l[h] = pl1; e1r[h] = pr1; e2l[h] = pl2; e2r[h] = pr2;
    }
    if (row < NT) {
      if (q == 0) {
        *(float4*)&el1[(size_t)row * 4] = make_float4(e1l[0], e1l[1], e1l[2], e1l[3]);
        *(float4*)&er1[(size_t)row * 4] = make_float4(e1r[0], e1r[1], e1r[2], e1r[3]);
        *(float4*)&el2[(size_t)row * 4] = make_float4(e2l[0], e2l[1], e2l[2], e2l[3]);
        *(float4*)&er2[(size_t)row * 4] = make_float4(e2r[0], e2r[1], e2r[2], e2r[3]);
      }
#pragma unroll
      for (int mt = 0; mt < 4; mt++) {
        uint2 u1 = {pack2(a1[mt][0], a1[mt][1]), pack2(a1[mt][2], a1[mt][3])};
        uint2 u2 = {pack2(a2[mt][0], a2[mt][1]), pack2(a2[mt][2], a2[mt][3])};
        *(uint2*)&z1[(size_t)row * 64 + mt * 16 + 4 * q] = u1;
        *(uint2*)&z2[(size_t)row * 64 + mt * 16 + 4 * q] = u2;
      }
    }
  }
}

// ---------------------------------------------------------------------------
// agg: one wave per (node, t-block of 4); software-pipelined edge loop.
// ---------------------------------------------------------------------------
__device__ __forceinline__ void gat_rel(int n, int t, const int* __restrict__ scsr,
                                        const int* __restrict__ off, const float* elp,
                                        float er_h, const unsigned short* zp, float& a0,
                                        float& a1, float& a2, float& a3) {
  int b0 = off[n], b1 = off[n + 1];
  if (b1 <= b0) return;
  float den = 0.f, n0 = 0.f, n1 = 0.f, n2 = 0.f, n3 = 0.f;
  int sb = scsr[b0];
  int srow = sb + t;
  float elv = elp[(size_t)srow * 4];
  uint2 zv = *(const uint2*)(zp + (size_t)srow * 64);
  for (int j = b0; j < b1; j++) {
    int jn = (j + 1 < b1) ? j + 1 : j;
    int sbn = scsr[jn];
    int srown = sbn + t;
    float elvn = elp[(size_t)srown * 4];
    uint2 zvn = *(const uint2*)(zp + (size_t)srown * 64);
    float ev = elv + er_h;
    ev = fmaxf(ev, kNeg * ev);
    float wgt = exp2f(ev);
    den += wgt;
    n0 = fmaf(wgt, __uint_as_float(zv.x << 16), n0);
    n1 = fmaf(wgt, __uint_as_float(zv.x & 0xffff0000u), n1);
    n2 = fmaf(wgt, __uint_as_float(zv.y << 16), n2);
    n3 = fmaf(wgt, __uint_as_float(zv.y & 0xffff0000u), n3);
    elv = elvn;
    zv = zvn;
  }
  float inv = 1.f / den;
  a0 = fmaf(n0, inv, a0);
  a1 = fmaf(n1, inv, a1);
  a2 = fmaf(n2, inv, a2);
  a3 = fmaf(n3, inv, a3);
}

__global__ __launch_bounds__(256) void agg_kernel(
    const float* __restrict__ x, const int* __restrict__ scsr1,
    const int* __restrict__ off1, const float* __restrict__ el1,
    const float* __restrict__ er1, const unsigned short* __restrict__ z1,
    const int* __restrict__ scsr2, const int* __restrict__ off2,
    const float* __restrict__ el2, const float* __restrict__ er2,
    const unsigned short* __restrict__ z2, float* __restrict__ x2,
    float* __restrict__ bn2s, float* __restrict__ bn2q, int N) {
  int wid = threadIdx.x >> 6, lane = threadIdx.x & 63;
  int w = blockIdx.x * 4 + wid;
  if (w >= N * 3) return;
  int n = w / 3;
  int t0 = (w - n * 3) * 4;
  int tl = lane >> 4, cg = lane & 15;
  int t = t0 + tl;
  int row = n * kT + t;
  int h = cg >> 2;
  float a0 = 0.f, a1 = 0.f, a2 = 0.f, a3 = 0.f;
  gat_rel(n, t, scsr1, off1, el1 + h, er1[(size_t)row * 4 + h], z1 + cg * 4, a0, a1, a2, a3);
  gat_rel(n, t, scsr2, off2, el2 + h, er2[(size_t)row * 4 + h], z2 + cg * 4, a0, a1, a2, a3);

  size_t base = (size_t)row * 64 + cg * 4;
  float4 xr = *(const float4*)&x[base];
  float4 o;
  o.x = xr.x + a0;
  o.y = xr.y + a1;
  o.z = xr.z + a2;
  o.w = xr.w + a3;
  *(float4*)&x2[base] = o;
  float s1 = o.x + o.y + o.z + o.w;
  float s2 = o.x * o.x + o.y * o.y + o.z * o.z + o.w * o.w;
  s1 = wave_reduce_sum(s1);
  s2 = wave_reduce_sum(s2);
  if (lane == 0) {
    atomicAdd(&bn2s[n], s1);
    atomicAdd(&bn2q[n], s2);
  }
}

// ---------------------------------------------------------------------------
// MFMA FF: coalesced frag staging, biases in LDS, incremental GEMM2.
// __launch_bounds__(256,2): 256-VGPR cap — roomy, NO spills (the (256,4)
// variant spilled ~200 MB to scratch; R6 post-mortem).
// ---------------------------------------------------------------------------
__global__ __launch_bounds__(256, 2) void ff_kernel(
    const float* __restrict__ x2, const float* __restrict__ bn2s,
    const float* __restrict__ bn2q, const float* __restrict__ bng,
    const float* __restrict__ bnb, const bf16x8* __restrict__ w1f,
    const bf16x8* __restrict__ w2f, const float* __restrict__ b1,
    const float* __restrict__ b2, float* __restrict__ out, int NT) {
  __shared__ bf16x8 sW1[16][64];
  __shared__ bf16x8 sW2[16][64];
  __shared__ float sB1[128];
  __shared__ float sB2[64];
  int lane = threadIdx.x & 63, wid = threadIdx.x >> 6;
  int m = lane & 15, q = lane >> 4;
  {
    int fi0 = wid * 4;
#pragma unroll
    for (int k = 0; k < 4; k++) {
      sW1[fi0 + k][lane] = w1f[(fi0 + k) * 64 + lane];
      sW2[fi0 + k][lane] = w2f[(fi0 + k) * 64 + lane];
    }
    if (threadIdx.x < 128) sB1[threadIdx.x] = b1[threadIdx.x];
    if (threadIdx.x < 64) sB2[threadIdx.x] = b2[threadIdx.x];
  }
  __syncthreads();

  const float inv = 1.f / (kT * 64);
  int ntile = (NT + 15) / 16;
  for (int tile = blockIdx.x * 4 + wid; tile < ntile; tile += gridDim.x * 4) {
    int r0 = tile * 16;
    int row = r0 + m;
    int rowc = (row < NT) ? row : NT - 1;
    int n = rowc / kT;
    float mean = bn2s[n] * inv;
    float var = bn2q[n] * inv - mean * mean;
    float sc = rsqrtf(var + kEps) * bng[n];
    float sh = bnb[n] - mean * sc;

    bf16x8 hf[2];
#pragma unroll
    for (int kc = 0; kc < 2; kc++) {
      const float4 p0 = *(const float4*)&x2[(size_t)rowc * 64 + kc * 32 + q * 8];
      const float4 p1 = *(const float4*)&x2[(size_t)rowc * 64 + kc * 32 + q * 8 + 4];
      hf[kc][0] = f2bf(fmaf(p0.x, sc, sh));
      hf[kc][1] = f2bf(fmaf(p0.y, sc, sh));
      hf[kc][2] = f2bf(fmaf(p0.z, sc, sh));
      hf[kc][3] = f2bf(fmaf(p0.w, sc, sh));
      hf[kc][4] = f2bf(fmaf(p1.x, sc, sh));
      hf[kc][5] = f2bf(fmaf(p1.y, sc, sh));
      hf[kc][6] = f2bf(fmaf(p1.z, sc, sh));
      hf[kc][7] = f2bf(fmaf(p1.w, sc, sh));
    }

    f32x4 acc[8];
#pragma unroll
    for (int mt = 0; mt < 8; mt++) acc[mt] = (f32x4){0.f, 0.f, 0.f, 0.f};
#pragma unroll
    for (int kc = 0; kc < 2; kc++)
#pragma unroll
      for (int mt = 0; mt < 8; mt++)
        acc[mt] = __builtin_amdgcn_mfma_f32_16x16x32_bf16(sW1[mt * 2 + kc][lane], hf[kc],
                                                          acc[mt], 0, 0, 0);

    f32x4 acc2[4];
#pragma unroll
    for (int mt = 0; mt < 4; mt++) acc2[mt] = (f32x4){0.f, 0.f, 0.f, 0.f};
#pragma unroll
    for (int kc = 0; kc < 4; kc++) {
      float4 bb0 = *(const float4*)&sB1[(2 * kc) * 16 + 4 * q];
      float4 bb1 = *(const float4*)&sB1[(2 * kc + 1) * 16 + 4 * q];
      float g0[4], g1[4];
      {
        float u;
        u = acc[2 * kc][0] + bb0.x; g0[0] = 0.5f * u * (1.f + erff(u * 0.70710678118654752f));
        u = acc[2 * kc][1] + bb0.y; g0[1] = 0.5f * u * (1.f + erff(u * 0.70710678118654752f));
        u = acc[2 * kc][2] + bb0.z; g0[2] = 0.5f * u * (1.f + erff(u * 0.70710678118654752f));
        u = acc[2 * kc][3] + bb0.w; g0[3] = 0.5f * u * (1.f + erff(u * 0.70710678118654752f));
        u = acc[2 * kc + 1][0] + bb1.x; g1[0] = 0.5f * u * (1.f + erff(u * 0.70710678118654752f));
        u = acc[2 * kc + 1][1] + bb1.y; g1[1] = 0.5f * u * (1.f + erff(u * 0.70710678118654752f));
        u = acc[2 * kc + 1][2] + bb1.z; g1[2] = 0.5f * u * (1.f + erff(u * 0.70710678118654752f));
        u = acc[2 * kc + 1][3] + bb1.w; g1[3] = 0.5f * u * (1.f + erff(u * 0.70710678118654752f));
      }
      bf16x8 bf;
#pragma unroll
      for (int j = 0; j < 8; j++) {
        int srcq = (2 * q + (j >> 2)) & 3;
        int src = srcq * 16 + m;
        float v0 = __shfl(g0[j & 3], src);
        float v1 = __shfl(g1[j & 3], src);
        bf[j] = f2bf((q >= 2) ? v1 : v0);
      }
#pragma unroll
      for (int mt = 0; mt < 4; mt++)
        acc2[mt] = __builtin_amdgcn_mfma_f32_16x16x32_bf16(sW2[mt * 4 + kc][lane], bf,
                                                           acc2[mt], 0, 0, 0);
    }

    if (row < NT) {
#pragma unroll
      for (int mt = 0; mt < 4; mt++) {
        size_t base = (size_t)row * 64 + mt * 16 + 4 * q;
        float4 xr = *(const float4*)&x2[base];
        float4 bb = *(const float4*)&sB2[mt * 16 + 4 * q];
        float4 o;
        o.x = acc2[mt][0] + bb.x + xr.x;
        o.y = acc2[mt][1] + bb.y + xr.y;
        o.z = acc2[mt][2] + bb.z + xr.z;
        o.w = acc2[mt][3] + bb.w + xr.w;
        *(float4*)&out[base] = o;
      }
    }
  }
}

extern "C" void kernel_launch(void* const* d_in, const int* in_sizes, int n_in,
                              void* d_out, int out_size, void* d_ws, size_t ws_size,
                              hipStream_t stream) {
  const float* x = (const float*)d_in[0];
  const int* src1 = (const int*)d_in[1];
  const int* dst1 = (const int*)d_in[2];
  const int* src2 = (const int*)d_in[3];
  const int* dst2 = (const int*)d_in[4];
  const float* W1 = (const float*)d_in[5];
  const float* al1 = (const float*)d_in[6];
  const float* ar1 = (const float*)d_in[7];
  const float* W2 = (const float*)d_in[8];
  const float* al2 = (const float*)d_in[9];
  const float* ar2 = (const float*)d_in[10];
  const float* g1 = (const float*)d_in[11];
  const float* b1 = (const float*)d_in[12];
  const float* g2 = (const float*)d_in[13];
  const float* b2 = (const float*)d_in[14];
  const float* fw1 = (const float*)d_in[15];
  const float* fb1 = (const float*)d_in[16];
  const float* fw2 = (const float*)d_in[17];
  const float* fb2 = (const float*)d_in[18];

  const int N = in_sizes[11];
  const int E1 = in_sizes[1];
  const int E2 = in_sizes[3];
  const int NT = N * kT;

  char* p = (char*)d_ws;
  auto alloc = [&](size_t bytes) -> char* {
    char* r = p;
    p += (bytes + 255) & ~(size_t)255;
    return r;
  };
  unsigned short* z1 = (unsigned short*)alloc((size_t)NT * 64 * 2);
  unsigned short* z2 = (unsigned short*)alloc((size_t)NT * 64 * 2);
  float* el1 = (float*)alloc((size_t)NT * 4 * 4);
  float* er1 = (float*)alloc((size_t)NT * 4 * 4);
  float* el2 = (float*)alloc((size_t)NT * 4 * 4);
  float* er2 = (float*)alloc((size_t)NT * 4 * 4);
  float* x2 = (float*)alloc((size_t)NT * 64 * 4);
  float* sc1 = (float*)alloc((size_t)N * 4);
  float* sh1 = (float*)alloc((size_t)N * 4);
  int* off1 = (int*)alloc((size_t)(N + 1) * 4);
  int* off2 = (int*)alloc((size_t)(N + 1) * 4);
  int* scsr1 = (int*)alloc((size_t)E1 * 4);
  int* scsr2 = (int*)alloc((size_t)E2 * 4);
  bf16x8* fw1f = (bf16x8*)alloc(16 * 64 * 16);
  bf16x8* fw2f = (bf16x8*)alloc(16 * 64 * 16);
  bf16x8* zw1f = (bf16x8*)alloc(8 * 64 * 16);
  bf16x8* zw2f = (bf16x8*)alloc(8 * 64 * 16);
  char* zero_base = p;
  int* deg1 = (int*)alloc((size_t)N * 4);
  int* cur1 = (int*)alloc((size_t)N * 4);
  int* deg2 = (int*)alloc((size_t)N * 4);
  int* cur2 = (int*)alloc((size_t)N * 4);
  float* bn2s = (float*)alloc((size_t)N * 4);
  float* bn2q = (float*)alloc((size_t)N * 4);
  size_t zero_bytes = (size_t)(p - zero_base);
  hipMemsetAsync(zero_base, 0, zero_bytes, stream);

  bnprep_kernel<<<N + 4, 256, 0, stream>>>(x, g1, b1, sc1, sh1, fw1, fw2, W1, W2, fw1f, fw2f,
                                           zw1f, zw2f, N);
  deg_kernel<<<(E1 + E2 + 255) / 256, 256, 0, stream>>>(dst1, dst2, deg1, deg2, E1, E2);
  scan_kernel<<<2, 1024, 0, stream>>>(deg1, off1, deg2, off2, N);
  fill_kernel<<<(E1 + E2 + 255) / 256, 256, 0, stream>>>(src1, dst1, off1, cur1, scsr1, src2,
                                                         dst2, off2, cur2, scsr2, E1, E2);
  zel_kernel<<<1875, 256, 0, stream>>>(x, sc1, sh1, zw1f, zw2f, al1, ar1, al2, ar2, z1, z2,
                                       el1, er1, el2, er2, NT);
  agg_kernel<<<(N * 3 + 3) / 4, 256, 0, stream>>>(x, scsr1, off1, el1, er1, z1, scsr2, off2,
                                                  el2, er2, z2, x2, bn2s, bn2q, N);
  ff_kernel<<<1875, 256, 0, stream>>>(x2, bn2s, bn2q, g2, b2, fw1f, fw2f, fb1, fb2,
                                      (float*)d_out, NT);
}

// Round 8
// 268.446 us; speedup vs baseline: 1.3051x; 1.0667x over previous
//
#include <hip/hip_runtime.h>
#include <math.h>

constexpr int kT = 12;
constexpr float kNeg = 0.2f;
constexpr float kEps = 1e-5f;
constexpr float kLog2e = 1.44269504088896f;

typedef __attribute__((ext_vector_type(8))) short bf16x8;
typedef __attribute__((ext_vector_type(4))) float f32x4;

__device__ __forceinline__ short f2bf(float f) {
  union { float f; unsigned u; } v;
  v.f = f;
  return (short)((v.u + 0x7fffu + ((v.u >> 16) & 1u)) >> 16);
}
__device__ __forceinline__ unsigned pack2(float a, float b) {
  return (unsigned)(unsigned short)f2bf(a) | ((unsigned)(unsigned short)f2bf(b) << 16);
}

__device__ __forceinline__ float wave_reduce_sum(float v) {
#pragma unroll
  for (int o = 32; o > 0; o >>= 1) v += __shfl_xor(v, o);
  return v;
}

// ---------------------------------------------------------------------------
// bn_stats + one-time MFMA-fragment pre-pack (blocks N..N+3).
// ---------------------------------------------------------------------------
__global__ void bnprep_kernel(const float* __restrict__ x, const float* __restrict__ g,
                              const float* __restrict__ b, float* __restrict__ scale,
                              float* __restrict__ shift, const float* __restrict__ fw1,
                              const float* __restrict__ fw2, const float* __restrict__ zW1,
                              const float* __restrict__ zW2, bf16x8* __restrict__ fw1f,
                              bf16x8* __restrict__ fw2f, bf16x8* __restrict__ zw1f,
                              bf16x8* __restrict__ zw2f, int N) {
  int blk = blockIdx.x;
  int lane = threadIdx.x & 63, wid = threadIdx.x >> 6;
  if (blk >= N) {
    int which = blk - N;
    int m = lane & 15, q = lane >> 4;
    if (which == 0) {
      for (int fi = wid; fi < 16; fi += 4) {
        int mt = fi >> 1, kc = fi & 1;
        bf16x8 v;
#pragma unroll
        for (int j = 0; j < 8; j++) v[j] = f2bf(fw1[(kc * 32 + q * 8 + j) * 128 + mt * 16 + m]);
        fw1f[fi * 64 + lane] = v;
      }
    } else if (which == 1) {
      for (int fi = wid; fi < 16; fi += 4) {
        int mt2 = fi >> 2, kc2 = fi & 3;
        bf16x8 u;
#pragma unroll
        for (int j = 0; j < 8; j++) u[j] = f2bf(fw2[(kc2 * 32 + q * 8 + j) * 64 + mt2 * 16 + m]);
        fw2f[fi * 64 + lane] = u;
      }
    } else if (which == 2) {
      for (int fi = wid; fi < 8; fi += 4) {
        int mt = fi >> 1, kc = fi & 1;
        bf16x8 v;
#pragma unroll
        for (int j = 0; j < 8; j++) v[j] = f2bf(zW1[(kc * 32 + q * 8 + j) * 64 + mt * 16 + m]);
        zw1f[fi * 64 + lane] = v;
      }
    } else {
      for (int fi = wid; fi < 8; fi += 4) {
        int mt = fi >> 1, kc = fi & 1;
        bf16x8 v;
#pragma unroll
        for (int j = 0; j < 8; j++) v[j] = f2bf(zW2[(kc * 32 + q * 8 + j) * 64 + mt * 16 + m]);
        zw2f[fi * 64 + lane] = v;
      }
    }
    return;
  }
  int n = blk;
  const float* xr = x + (size_t)n * (kT * 64);
  float s = 0.f, s2 = 0.f;
  for (int i = threadIdx.x; i < kT * 64; i += blockDim.x) {
    float v = xr[i];
    s += v;
    s2 += v * v;
  }
  s = wave_reduce_sum(s);
  s2 = wave_reduce_sum(s2);
  __shared__ float ls[4], ls2[4];
  if (lane == 0) { ls[wid] = s; ls2[wid] = s2; }
  __syncthreads();
  if (threadIdx.x == 0) {
    float ts = 0.f, ts2 = 0.f;
    for (int i = 0; i < 4; i++) { ts += ls[i]; ts2 += ls2[i]; }
    const float inv = 1.f / (kT * 64);
    float mean = ts * inv;
    float var = ts2 * inv - mean * mean;
    float sc = rsqrtf(var + kEps) * g[n];
    scale[n] = sc;
    shift[n] = b[n] - mean * sc;
  }
}

// fused degree count for both relations
__global__ void deg_kernel(const int* __restrict__ dst1, const int* __restrict__ dst2,
                           int* __restrict__ deg1, int* __restrict__ deg2, int E1, int E2) {
  int i = blockIdx.x * blockDim.x + threadIdx.x;
  if (i < E1) atomicAdd(&deg1[dst1[i]], 1);
  else if (i < E1 + E2) atomicAdd(&deg2[dst2[i - E1]], 1);
}

// two single-block scans (blockIdx 0 -> rel1, 1 -> rel2), shfl wave-scans
__global__ void scan_kernel(const int* __restrict__ deg1, int* __restrict__ off1,
                            const int* __restrict__ deg2, int* __restrict__ off2, int N) {
  const int* deg = blockIdx.x ? deg2 : deg1;
  int* off = blockIdx.x ? off2 : off1;
  __shared__ int wsum[16];
  __shared__ int carry;
  int tid = threadIdx.x, lane = tid & 63, wv = tid >> 6;
  if (tid == 0) { carry = 0; off[0] = 0; }
  __syncthreads();
  for (int base = 0; base < N; base += 1024) {
    int i = base + tid;
    int incl = (i < N) ? deg[i] : 0;
#pragma unroll
    for (int o = 1; o < 64; o <<= 1) {
      int y = __shfl_up(incl, o);
      if (lane >= o) incl += y;
    }
    if (lane == 63) wsum[wv] = incl;
    __syncthreads();
    if (tid < 16) {
      int p = wsum[tid];
#pragma unroll
      for (int o = 1; o < 16; o <<= 1) {
        int y = __shfl_up(p, o);
        if (tid >= o) p += y;
      }
      wsum[tid] = p;
    }
    __syncthreads();
    int prefix = carry + (wv > 0 ? wsum[wv - 1] : 0);
    if (i < N) off[i + 1] = prefix + incl;
    int total = carry + wsum[15];
    __syncthreads();
    if (tid == 0) carry = total;
    __syncthreads();
  }
}

// fused CSR fill; stores src*kT (z-row base)
__global__ void fill_kernel(const int* __restrict__ src1, const int* __restrict__ dst1,
                            const int* __restrict__ off1, int* __restrict__ cur1,
                            int* __restrict__ scsr1, const int* __restrict__ src2,
                            const int* __restrict__ dst2, const int* __restrict__ off2,
                            int* __restrict__ cur2, int* __restrict__ scsr2, int E1, int E2) {
  int i = blockIdx.x * blockDim.x + threadIdx.x;
  if (i < E1) {
    int d = dst1[i];
    int p = atomicAdd(&cur1[d], 1);
    scsr1[off1[d] + p] = src1[i] * kT;
  } else if (i < E1 + E2) {
    int k = i - E1;
    int d = dst2[k];
    int p = atomicAdd(&cur2[d], 1);
    scsr2[off2[d] + p] = src2[k] * kT;
  }
}

// ---------------------------------------------------------------------------
// MFMA zel: frag staging coalesced from prepacked buffers.
// ---------------------------------------------------------------------------
__global__ __launch_bounds__(256) void zel_kernel(
    const float* __restrict__ x, const float* __restrict__ scale,
    const float* __restrict__ shift, const bf16x8* __restrict__ zw1f,
    const bf16x8* __restrict__ zw2f, const float* __restrict__ al1,
    const float* __restrict__ ar1, const float* __restrict__ al2,
    const float* __restrict__ ar2, unsigned short* __restrict__ z1,
    unsigned short* __restrict__ z2, float* __restrict__ el1, float* __restrict__ er1,
    float* __restrict__ el2, float* __restrict__ er2, int NT) {
  __shared__ bf16x8 sW1[8][64];
  __shared__ bf16x8 sW2[8][64];
  int lane = threadIdx.x & 63, wid = threadIdx.x >> 6;
  int m = lane & 15, q = lane >> 4;
  for (int fi = wid; fi < 8; fi += 4) {
    sW1[fi][lane] = zw1f[fi * 64 + lane];
    sW2[fi][lane] = zw2f[fi * 64 + lane];
  }
  __syncthreads();
  float al1r[4][4], ar1r[4][4], al2r[4][4], ar2r[4][4];
#pragma unroll
  for (int h = 0; h < 4; h++)
#pragma unroll
    for (int r = 0; r < 4; r++) {
      int f = h * 16 + 4 * q + r;
      al1r[h][r] = al1[f] * kLog2e;
      ar1r[h][r] = ar1[f] * kLog2e;
      al2r[h][r] = al2[f] * kLog2e;
      ar2r[h][r] = ar2[f] * kLog2e;
    }
  int ntile = (NT + 15) / 16;
  for (int tile = blockIdx.x * 4 + wid; tile < ntile; tile += gridDim.x * 4) {
    int r0 = tile * 16;
    int row = r0 + m;
    int rowc = (row < NT) ? row : NT - 1;
    int n = rowc / kT;
    float sc = scale[n], sh = shift[n];
    bf16x8 hf[2];
#pragma unroll
    for (int kc = 0; kc < 2; kc++) {
      float4 p0 = *(const float4*)&x[(size_t)rowc * 64 + kc * 32 + q * 8];
      float4 p1 = *(const float4*)&x[(size_t)rowc * 64 + kc * 32 + q * 8 + 4];
      hf[kc][0] = f2bf(fmaf(p0.x, sc, sh));
      hf[kc][1] = f2bf(fmaf(p0.y, sc, sh));
      hf[kc][2] = f2bf(fmaf(p0.z, sc, sh));
      hf[kc][3] = f2bf(fmaf(p0.w, sc, sh));
      hf[kc][4] = f2bf(fmaf(p1.x, sc, sh));
      hf[kc][5] = f2bf(fmaf(p1.y, sc, sh));
      hf[kc][6] = f2bf(fmaf(p1.z, sc, sh));
      hf[kc][7] = f2bf(fmaf(p1.w, sc, sh));
    }
    f32x4 a1[4], a2[4];
#pragma unroll
    for (int mt = 0; mt < 4; mt++) {
      a1[mt] = (f32x4){0.f, 0.f, 0.f, 0.f};
      a2[mt] = (f32x4){0.f, 0.f, 0.f, 0.f};
    }
#pragma unroll
    for (int kc = 0; kc < 2; kc++)
#pragma unroll
      for (int mt = 0; mt < 4; mt++) {
        a1[mt] = __builtin_amdgcn_mfma_f32_16x16x32_bf16(sW1[mt * 2 + kc][lane], hf[kc],
                                                         a1[mt], 0, 0, 0);
        a2[mt] = __builtin_amdgcn_mfma_f32_16x16x32_bf16(sW2[mt * 2 + kc][lane], hf[kc],
                                                         a2[mt], 0, 0, 0);
      }
    float e1l[4], e1r[4], e2l[4], e2r[4];
#pragma unroll
    for (int h = 0; h < 4; h++) {
      float pl1 = 0.f, pr1 = 0.f, pl2 = 0.f, pr2 = 0.f;
#pragma unroll
      for (int r = 0; r < 4; r++) {
        pl1 = fmaf(a1[h][r], al1r[h][r], pl1);
        pr1 = fmaf(a1[h][r], ar1r[h][r], pr1);
        pl2 = fmaf(a2[h][r], al2r[h][r], pl2);
        pr2 = fmaf(a2[h][r], ar2r[h][r], pr2);
      }
#pragma unroll
      for (int o = 16; o < 64; o <<= 1) {
        pl1 += __shfl_xor(pl1, o);
        pr1 += __shfl_xor(pr1, o);
        pl2 += __shfl_xor(pl2, o);
        pr2 += __shfl_xor(pr2, o);
      }
      e1l[h] = pl1; e1r[h] = pr1; e2l[h] = pl2; e2r[h] = pr2;
    }
    if (row < NT) {
      if (q == 0) {
        *(float4*)&el1[(size_t)row * 4] = make_float4(e1l[0], e1l[1], e1l[2], e1l[3]);
        *(float4*)&er1[(size_t)row * 4] = make_float4(e1r[0], e1r[1], e1r[2], e1r[3]);
        *(float4*)&el2[(size_t)row * 4] = make_float4(e2l[0], e2l[1], e2l[2], e2l[3]);
        *(float4*)&er2[(size_t)row * 4] = make_float4(e2r[0], e2r[1], e2r[2], e2r[3]);
      }
#pragma unroll
      for (int mt = 0; mt < 4; mt++) {
        uint2 u1 = {pack2(a1[mt][0], a1[mt][1]), pack2(a1[mt][2], a1[mt][3])};
        uint2 u2 = {pack2(a2[mt][0], a2[mt][1]), pack2(a2[mt][2], a2[mt][3])};
        *(uint2*)&z1[(size_t)row * 64 + mt * 16 + 4 * q] = u1;
        *(uint2*)&z2[(size_t)row * 64 + mt * 16 + 4 * q] = u2;
      }
    }
  }
}

// ---------------------------------------------------------------------------
// agg v3: lane-cooperative edge-id load (one coalesced scsr load covers 64
// edges), ids broadcast via __shfl -> el/z prefetch pipelined 2 deep with no
// scsr->el/z serial dependency (R7 post-mortem: that chain was the stall).
// ---------------------------------------------------------------------------
__device__ __forceinline__ void gat_rel(int n, int t, const int* __restrict__ scsr,
                                        const int* __restrict__ off,
                                        const float* __restrict__ elp, float er_h,
                                        const unsigned short* __restrict__ zp, int lane,
                                        float& a0, float& a1, float& a2, float& a3) {
  int b0 = off[n], b1 = off[n + 1];
  if (b1 <= b0) return;
  float den = 0.f, n0 = 0.f, n1 = 0.f, n2 = 0.f, n3 = 0.f;
  for (int c0 = b0; c0 < b1; c0 += 64) {
    int cnt = b1 - c0;
    if (cnt > 64) cnt = 64;
    int idx = c0 + lane;
    int sbl = scsr[(idx < b1) ? idx : b1 - 1];  // coalesced, one per 64 edges
    // 2-deep pipeline: ids via shfl (no global latency), loads prefetched
    int s0 = __shfl(sbl, 0) + t;
    int s1 = (cnt > 1) ? (__shfl(sbl, 1) + t) : s0;
    float e0 = elp[(size_t)s0 * 4];
    uint2 zz0 = *(const uint2*)(zp + (size_t)s0 * 64);
    float e1 = elp[(size_t)s1 * 4];
    uint2 zz1 = *(const uint2*)(zp + (size_t)s1 * 64);
    for (int k = 0; k < cnt; k++) {
      int s2 = (k + 2 < cnt) ? (__shfl(sbl, k + 2) + t) : s1;
      float e2 = elp[(size_t)s2 * 4];
      uint2 zz2 = *(const uint2*)(zp + (size_t)s2 * 64);
      float ev = e0 + er_h;
      ev = fmaxf(ev, kNeg * ev);
      float wgt = exp2f(ev);
      den += wgt;
      n0 = fmaf(wgt, __uint_as_float(zz0.x << 16), n0);
      n1 = fmaf(wgt, __uint_as_float(zz0.x & 0xffff0000u), n1);
      n2 = fmaf(wgt, __uint_as_float(zz0.y << 16), n2);
      n3 = fmaf(wgt, __uint_as_float(zz0.y & 0xffff0000u), n3);
      s0 = s1; e0 = e1; zz0 = zz1;
      s1 = s2; e1 = e2; zz1 = zz2;
    }
  }
  float inv = 1.f / den;
  a0 = fmaf(n0, inv, a0);
  a1 = fmaf(n1, inv, a1);
  a2 = fmaf(n2, inv, a2);
  a3 = fmaf(n3, inv, a3);
}

__global__ __launch_bounds__(256) void agg_kernel(
    const float* __restrict__ x, const int* __restrict__ scsr1,
    const int* __restrict__ off1, const float* __restrict__ el1,
    const float* __restrict__ er1, const unsigned short* __restrict__ z1,
    const int* __restrict__ scsr2, const int* __restrict__ off2,
    const float* __restrict__ el2, const float* __restrict__ er2,
    const unsigned short* __restrict__ z2, float* __restrict__ x2,
    float* __restrict__ bn2s, float* __restrict__ bn2q, int N) {
  int wid = threadIdx.x >> 6, lane = threadIdx.x & 63;
  int w = blockIdx.x * 4 + wid;
  if (w >= N * 3) return;
  int n = w / 3;
  int t0 = (w - n * 3) * 4;
  int tl = lane >> 4, cg = lane & 15;
  int t = t0 + tl;
  int row = n * kT + t;
  int h = cg >> 2;
  float a0 = 0.f, a1 = 0.f, a2 = 0.f, a3 = 0.f;
  gat_rel(n, t, scsr1, off1, el1 + h, er1[(size_t)row * 4 + h], z1 + cg * 4, lane, a0, a1, a2,
          a3);
  gat_rel(n, t, scsr2, off2, el2 + h, er2[(size_t)row * 4 + h], z2 + cg * 4, lane, a0, a1, a2,
          a3);

  size_t base = (size_t)row * 64 + cg * 4;
  float4 xr = *(const float4*)&x[base];
  float4 o;
  o.x = xr.x + a0;
  o.y = xr.y + a1;
  o.z = xr.z + a2;
  o.w = xr.w + a3;
  *(float4*)&x2[base] = o;
  float s1 = o.x + o.y + o.z + o.w;
  float s2 = o.x * o.x + o.y * o.y + o.z * o.z + o.w * o.w;
  s1 = wave_reduce_sum(s1);
  s2 = wave_reduce_sum(s2);
  if (lane == 0) {
    atomicAdd(&bn2s[n], s1);
    atomicAdd(&bn2q[n], s2);
  }
}

// ---------------------------------------------------------------------------
// MFMA FF: coalesced frag staging, biases in LDS, incremental GEMM2.
// __launch_bounds__(256,2): 256-VGPR cap — no spills (R6 post-mortem).
// ---------------------------------------------------------------------------
__global__ __launch_bounds__(256, 2) void ff_kernel(
    const float* __restrict__ x2, const float* __restrict__ bn2s,
    const float* __restrict__ bn2q, const float* __restrict__ bng,
    const float* __restrict__ bnb, const bf16x8* __restrict__ w1f,
    const bf16x8* __restrict__ w2f, const float* __restrict__ b1,
    const float* __restrict__ b2, float* __restrict__ out, int NT) {
  __shared__ bf16x8 sW1[16][64];
  __shared__ bf16x8 sW2[16][64];
  __shared__ float sB1[128];
  __shared__ float sB2[64];
  int lane = threadIdx.x & 63, wid = threadIdx.x >> 6;
  int m = lane & 15, q = lane >> 4;
  {
    int fi0 = wid * 4;
#pragma unroll
    for (int k = 0; k < 4; k++) {
      sW1[fi0 + k][lane] = w1f[(fi0 + k) * 64 + lane];
      sW2[fi0 + k][lane] = w2f[(fi0 + k) * 64 + lane];
    }
    if (threadIdx.x < 128) sB1[threadIdx.x] = b1[threadIdx.x];
    if (threadIdx.x < 64) sB2[threadIdx.x] = b2[threadIdx.x];
  }
  __syncthreads();

  const float inv = 1.f / (kT * 64);
  int ntile = (NT + 15) / 16;
  for (int tile = blockIdx.x * 4 + wid; tile < ntile; tile += gridDim.x * 4) {
    int r0 = tile * 16;
    int row = r0 + m;
    int rowc = (row < NT) ? row : NT - 1;
    int n = rowc / kT;
    float mean = bn2s[n] * inv;
    float var = bn2q[n] * inv - mean * mean;
    float sc = rsqrtf(var + kEps) * bng[n];
    float sh = bnb[n] - mean * sc;

    bf16x8 hf[2];
#pragma unroll
    for (int kc = 0; kc < 2; kc++) {
      const float4 p0 = *(const float4*)&x2[(size_t)rowc * 64 + kc * 32 + q * 8];
      const float4 p1 = *(const float4*)&x2[(size_t)rowc * 64 + kc * 32 + q * 8 + 4];
      hf[kc][0] = f2bf(fmaf(p0.x, sc, sh));
      hf[kc][1] = f2bf(fmaf(p0.y, sc, sh));
      hf[kc][2] = f2bf(fmaf(p0.z, sc, sh));
      hf[kc][3] = f2bf(fmaf(p0.w, sc, sh));
      hf[kc][4] = f2bf(fmaf(p1.x, sc, sh));
      hf[kc][5] = f2bf(fmaf(p1.y, sc, sh));
      hf[kc][6] = f2bf(fmaf(p1.z, sc, sh));
      hf[kc][7] = f2bf(fmaf(p1.w, sc, sh));
    }

    f32x4 acc[8];
#pragma unroll
    for (int mt = 0; mt < 8; mt++) acc[mt] = (f32x4){0.f, 0.f, 0.f, 0.f};
#pragma unroll
    for (int kc = 0; kc < 2; kc++)
#pragma unroll
      for (int mt = 0; mt < 8; mt++)
        acc[mt] = __builtin_amdgcn_mfma_f32_16x16x32_bf16(sW1[mt * 2 + kc][lane], hf[kc],
                                                          acc[mt], 0, 0, 0);

    f32x4 acc2[4];
#pragma unroll
    for (int mt = 0; mt < 4; mt++) acc2[mt] = (f32x4){0.f, 0.f, 0.f, 0.f};
#pragma unroll
    for (int kc = 0; kc < 4; kc++) {
      float4 bb0 = *(const float4*)&sB1[(2 * kc) * 16 + 4 * q];
      float4 bb1 = *(const float4*)&sB1[(2 * kc + 1) * 16 + 4 * q];
      float g0[4], g1[4];
      {
        float u;
        u = acc[2 * kc][0] + bb0.x; g0[0] = 0.5f * u * (1.f + erff(u * 0.70710678118654752f));
        u = acc[2 * kc][1] + bb0.y; g0[1] = 0.5f * u * (1.f + erff(u * 0.70710678118654752f));
        u = acc[2 * kc][2] + bb0.z; g0[2] = 0.5f * u * (1.f + erff(u * 0.70710678118654752f));
        u = acc[2 * kc][3] + bb0.w; g0[3] = 0.5f * u * (1.f + erff(u * 0.70710678118654752f));
        u = acc[2 * kc + 1][0] + bb1.x; g1[0] = 0.5f * u * (1.f + erff(u * 0.70710678118654752f));
        u = acc[2 * kc + 1][1] + bb1.y; g1[1] = 0.5f * u * (1.f + erff(u * 0.70710678118654752f));
        u = acc[2 * kc + 1][2] + bb1.z; g1[2] = 0.5f * u * (1.f + erff(u * 0.70710678118654752f));
        u = acc[2 * kc + 1][3] + bb1.w; g1[3] = 0.5f * u * (1.f + erff(u * 0.70710678118654752f));
      }
      bf16x8 bf;
#pragma unroll
      for (int j = 0; j < 8; j++) {
        int srcq = (2 * q + (j >> 2)) & 3;
        int src = srcq * 16 + m;
        float v0 = __shfl(g0[j & 3], src);
        float v1 = __shfl(g1[j & 3], src);
        bf[j] = f2bf((q >= 2) ? v1 : v0);
      }
#pragma unroll
      for (int mt = 0; mt < 4; mt++)
        acc2[mt] = __builtin_amdgcn_mfma_f32_16x16x32_bf16(sW2[mt * 4 + kc][lane], bf,
                                                           acc2[mt], 0, 0, 0);
    }

    if (row < NT) {
#pragma unroll
      for (int mt = 0; mt < 4; mt++) {
        size_t base = (size_t)row * 64 + mt * 16 + 4 * q;
        float4 xr = *(const float4*)&x2[base];
        float4 bb = *(const float4*)&sB2[mt * 16 + 4 * q];
        float4 o;
        o.x = acc2[mt][0] + bb.x + xr.x;
        o.y = acc2[mt][1] + bb.y + xr.y;
        o.z = acc2[mt][2] + bb.z + xr.z;
        o.w = acc2[mt][3] + bb.w + xr.w;
        *(float4*)&out[base] = o;
      }
    }
  }
}

extern "C" void kernel_launch(void* const* d_in, const int* in_sizes, int n_in,
                              void* d_out, int out_size, void* d_ws, size_t ws_size,
                              hipStream_t stream) {
  const float* x = (const float*)d_in[0];
  const int* src1 = (const int*)d_in[1];
  const int* dst1 = (const int*)d_in[2];
  const int* src2 = (const int*)d_in[3];
  const int* dst2 = (const int*)d_in[4];
  const float* W1 = (const float*)d_in[5];
  const float* al1 = (const float*)d_in[6];
  const float* ar1 = (const float*)d_in[7];
  const float* W2 = (const float*)d_in[8];
  const float* al2 = (const float*)d_in[9];
  const float* ar2 = (const float*)d_in[10];
  const float* g1 = (const float*)d_in[11];
  const float* b1 = (const float*)d_in[12];
  const float* g2 = (const float*)d_in[13];
  const float* b2 = (const float*)d_in[14];
  const float* fw1 = (const float*)d_in[15];
  const float* fb1 = (const float*)d_in[16];
  const float* fw2 = (const float*)d_in[17];
  const float* fb2 = (const float*)d_in[18];

  const int N = in_sizes[11];
  const int E1 = in_sizes[1];
  const int E2 = in_sizes[3];
  const int NT = N * kT;

  char* p = (char*)d_ws;
  auto alloc = [&](size_t bytes) -> char* {
    char* r = p;
    p += (bytes + 255) & ~(size_t)255;
    return r;
  };
  unsigned short* z1 = (unsigned short*)alloc((size_t)NT * 64 * 2);
  unsigned short* z2 = (unsigned short*)alloc((size_t)NT * 64 * 2);
  float* el1 = (float*)alloc((size_t)NT * 4 * 4);
  float* er1 = (float*)alloc((size_t)NT * 4 * 4);
  float* el2 = (float*)alloc((size_t)NT * 4 * 4);
  float* er2 = (float*)alloc((size_t)NT * 4 * 4);
  float* x2 = (float*)alloc((size_t)NT * 64 * 4);
  float* sc1 = (float*)alloc((size_t)N * 4);
  float* sh1 = (float*)alloc((size_t)N * 4);
  int* off1 = (int*)alloc((size_t)(N + 1) * 4);
  int* off2 = (int*)alloc((size_t)(N + 1) * 4);
  int* scsr1 = (int*)alloc((size_t)E1 * 4);
  int* scsr2 = (int*)alloc((size_t)E2 * 4);
  bf16x8* fw1f = (bf16x8*)alloc(16 * 64 * 16);
  bf16x8* fw2f = (bf16x8*)alloc(16 * 64 * 16);
  bf16x8* zw1f = (bf16x8*)alloc(8 * 64 * 16);
  bf16x8* zw2f = (bf16x8*)alloc(8 * 64 * 16);
  char* zero_base = p;
  int* deg1 = (int*)alloc((size_t)N * 4);
  int* cur1 = (int*)alloc((size_t)N * 4);
  int* deg2 = (int*)alloc((size_t)N * 4);
  int* cur2 = (int*)alloc((size_t)N * 4);
  float* bn2s = (float*)alloc((size_t)N * 4);
  float* bn2q = (float*)alloc((size_t)N * 4);
  size_t zero_bytes = (size_t)(p - zero_base);
  hipMemsetAsync(zero_base, 0, zero_bytes, stream);

  bnprep_kernel<<<N + 4, 256, 0, stream>>>(x, g1, b1, sc1, sh1, fw1, fw2, W1, W2, fw1f, fw2f,
                                           zw1f, zw2f, N);
  deg_kernel<<<(E1 + E2 + 255) / 256, 256, 0, stream>>>(dst1, dst2, deg1, deg2, E1, E2);
  scan_kernel<<<2, 1024, 0, stream>>>(deg1, off1, deg2, off2, N);
  fill_kernel<<<(E1 + E2 + 255) / 256, 256, 0, stream>>>(src1, dst1, off1, cur1, scsr1, src2,
                                                         dst2, off2, cur2, scsr2, E1, E2);
  zel_kernel<<<1875, 256, 0, stream>>>(x, sc1, sh1, zw1f, zw2f, al1, ar1, al2, ar2, z1, z2,
                                       el1, er1, el2, er2, NT);
  agg_kernel<<<(N * 3 + 3) / 4, 256, 0, stream>>>(x, scsr1, off1, el1, er1, z1, scsr2, off2,
                                                  el2, er2, z2, x2, bn2s, bn2q, N);
  ff_kernel<<<1875, 256, 0, stream>>>(x2, bn2s, bn2q, g2, b2, fw1f, fw2f, fb1, fb2,
                                      (float*)d_out, NT);
}

// Round 9
// 252.479 us; speedup vs baseline: 1.3877x; 1.0632x over previous
//
#include <hip/hip_runtime.h>
#include <math.h>

constexpr int kT = 12;
constexpr float kNeg = 0.2f;
constexpr float kEps = 1e-5f;
constexpr float kLog2e = 1.44269504088896f;

typedef __attribute__((ext_vector_type(8))) short bf16x8;
typedef __attribute__((ext_vector_type(4))) float f32x4;

__device__ __forceinline__ short f2bf(float f) {
  union { float f; unsigned u; } v;
  v.f = f;
  return (short)((v.u + 0x7fffu + ((v.u >> 16) & 1u)) >> 16);
}
__device__ __forceinline__ unsigned pack2(float a, float b) {
  return (unsigned)(unsigned short)f2bf(a) | ((unsigned)(unsigned short)f2bf(b) << 16);
}

__device__ __forceinline__ float wave_reduce_sum(float v) {
#pragma unroll
  for (int o = 32; o > 0; o >>= 1) v += __shfl_xor(v, o);
  return v;
}

// ---------------------------------------------------------------------------
// prep: BN1 stats (wave per node, no barriers) + frag pre-packs (4 blocks:
// ffw1, ffw2, zelW1+W2, wal=W·al for MFMA el/er) + deg count — one launch.
// ---------------------------------------------------------------------------
__global__ void prep_kernel(const float* __restrict__ x, const float* __restrict__ g,
                            const float* __restrict__ b, float* __restrict__ scale,
                            float* __restrict__ shift, const float* __restrict__ fw1,
                            const float* __restrict__ fw2, const float* __restrict__ zW1,
                            const float* __restrict__ zW2, const float* __restrict__ al1,
                            const float* __restrict__ ar1, const float* __restrict__ al2,
                            const float* __restrict__ ar2, bf16x8* __restrict__ fw1f,
                            bf16x8* __restrict__ fw2f, bf16x8* __restrict__ zw1f,
                            bf16x8* __restrict__ zw2f, bf16x8* __restrict__ walf,
                            const int* __restrict__ dst1, const int* __restrict__ dst2,
                            int* __restrict__ deg1, int* __restrict__ deg2, int N, int E1,
                            int E2, int nBnBlk) {
  int blk = blockIdx.x;
  int lane = threadIdx.x & 63, wid = threadIdx.x >> 6;
  if (blk < nBnBlk) {
    int n = blk * 4 + wid;
    if (n < N) {
      const float* xr = x + (size_t)n * 768;
      float s = 0.f, s2 = 0.f;
#pragma unroll
      for (int c = 0; c < 3; c++) {
        float4 v = *(const float4*)&xr[c * 256 + lane * 4];
        s += v.x + v.y + v.z + v.w;
        s2 += v.x * v.x + v.y * v.y + v.z * v.z + v.w * v.w;
      }
      s = wave_reduce_sum(s);
      s2 = wave_reduce_sum(s2);
      if (lane == 0) {
        const float inv = 1.f / 768.f;
        float mean = s * inv;
        float var = s2 * inv - mean * mean;
        float sc = rsqrtf(var + kEps) * g[n];
        scale[n] = sc;
        shift[n] = b[n] - mean * sc;
      }
    }
    return;
  }
  blk -= nBnBlk;
  int m = lane & 15, q = lane >> 4;
  if (blk == 0) {
    for (int fi = wid; fi < 16; fi += 4) {
      int mt = fi >> 1, kc = fi & 1;
      bf16x8 v;
#pragma unroll
      for (int j = 0; j < 8; j++) v[j] = f2bf(fw1[(kc * 32 + q * 8 + j) * 128 + mt * 16 + m]);
      fw1f[fi * 64 + lane] = v;
    }
    return;
  }
  if (blk == 1) {
    for (int fi = wid; fi < 16; fi += 4) {
      int mt2 = fi >> 2, kc2 = fi & 3;
      bf16x8 u;
#pragma unroll
      for (int j = 0; j < 8; j++) u[j] = f2bf(fw2[(kc2 * 32 + q * 8 + j) * 64 + mt2 * 16 + m]);
      fw2f[fi * 64 + lane] = u;
    }
    return;
  }
  if (blk == 2) {
    for (int fi = wid; fi < 8; fi += 4) {
      int mt = fi >> 1, kc = fi & 1;
      bf16x8 v, u;
#pragma unroll
      for (int j = 0; j < 8; j++) {
        int d = kc * 32 + q * 8 + j;
        v[j] = f2bf(zW1[d * 64 + mt * 16 + m]);
        u[j] = f2bf(zW2[d * 64 + mt * 16 + m]);
      }
      zw1f[fi * 64 + lane] = v;
      zw2f[fi * 64 + lane] = u;
    }
    return;
  }
  if (blk == 3) {
    // wal[f][d]: f=0..3 el1(h), 4..7 er1, 8..11 el2, 12..15 er2; pre-scaled log2e
    __shared__ float wal[16][64];
    for (int e0 = threadIdx.x; e0 < 1024; e0 += 256) {
      int f = e0 >> 6, d = e0 & 63;
      int h = f & 3;
      const float* av = (f < 4) ? al1 : (f < 8) ? ar1 : (f < 12) ? al2 : ar2;
      const float* W = (f < 8) ? zW1 : zW2;
      float s = 0.f;
#pragma unroll
      for (int e = 0; e < 16; e++) s += W[d * 64 + h * 16 + e] * av[h * 16 + e];
      wal[f][d] = s * kLog2e;
    }
    __syncthreads();
    if (wid == 0) {
#pragma unroll
      for (int kc = 0; kc < 2; kc++) {
        bf16x8 v;
#pragma unroll
        for (int j = 0; j < 8; j++) v[j] = f2bf(wal[m][kc * 32 + q * 8 + j]);
        walf[kc * 64 + lane] = v;
      }
    }
    return;
  }
  // deg blocks
  int i = (blk - 4) * 256 + threadIdx.x;
  if (i < E1) atomicAdd(&deg1[dst1[i]], 1);
  else if (i < E1 + E2) atomicAdd(&deg2[dst2[i - E1]], 1);
}

// two single-block scans (blockIdx 0 -> rel1, 1 -> rel2), shfl wave-scans
__global__ void scan_kernel(const int* __restrict__ deg1, int* __restrict__ off1,
                            const int* __restrict__ deg2, int* __restrict__ off2, int N) {
  const int* deg = blockIdx.x ? deg2 : deg1;
  int* off = blockIdx.x ? off2 : off1;
  __shared__ int wsum[16];
  __shared__ int carry;
  int tid = threadIdx.x, lane = tid & 63, wv = tid >> 6;
  if (tid == 0) { carry = 0; off[0] = 0; }
  __syncthreads();
  for (int base = 0; base < N; base += 1024) {
    int i = base + tid;
    int incl = (i < N) ? deg[i] : 0;
#pragma unroll
    for (int o = 1; o < 64; o <<= 1) {
      int y = __shfl_up(incl, o);
      if (lane >= o) incl += y;
    }
    if (lane == 63) wsum[wv] = incl;
    __syncthreads();
    if (tid < 16) {
      int p = wsum[tid];
#pragma unroll
      for (int o = 1; o < 16; o <<= 1) {
        int y = __shfl_up(p, o);
        if (tid >= o) p += y;
      }
      wsum[tid] = p;
    }
    __syncthreads();
    int prefix = carry + (wv > 0 ? wsum[wv - 1] : 0);
    if (i < N) off[i + 1] = prefix + incl;
    int total = carry + wsum[15];
    __syncthreads();
    if (tid == 0) carry = total;
    __syncthreads();
  }
}

// ---------------------------------------------------------------------------
// fill + zel fused (disjoint block ranges; independent work overlaps).
// zel: MFMA z + MFMA el/er (wal trick — no shfl reductions).
// ---------------------------------------------------------------------------
__global__ __launch_bounds__(256) void fillzel_kernel(
    // fill args
    const int* __restrict__ src1, const int* __restrict__ dst1, const int* __restrict__ off1,
    int* __restrict__ cur1, int* __restrict__ scsr1, const int* __restrict__ src2,
    const int* __restrict__ dst2, const int* __restrict__ off2, int* __restrict__ cur2,
    int* __restrict__ scsr2, int E1, int E2, int nZelBlk,
    // zel args
    const float* __restrict__ x, const float* __restrict__ scale,
    const float* __restrict__ shift, const bf16x8* __restrict__ zw1f,
    const bf16x8* __restrict__ zw2f, const bf16x8* __restrict__ walf,
    unsigned short* __restrict__ z1, unsigned short* __restrict__ z2,
    float* __restrict__ el1, float* __restrict__ er1, float* __restrict__ el2,
    float* __restrict__ er2, int NT) {
  if ((int)blockIdx.x >= nZelBlk) {
    int i = ((int)blockIdx.x - nZelBlk) * 256 + threadIdx.x;
    if (i < E1) {
      int d = dst1[i];
      int p = atomicAdd(&cur1[d], 1);
      scsr1[off1[d] + p] = src1[i] * kT;
    } else if (i < E1 + E2) {
      int k = i - E1;
      int d = dst2[k];
      int p = atomicAdd(&cur2[d], 1);
      scsr2[off2[d] + p] = src2[k] * kT;
    }
    return;
  }
  __shared__ bf16x8 sW1[8][64];
  __shared__ bf16x8 sW2[8][64];
  __shared__ bf16x8 sWE[2][64];
  int lane = threadIdx.x & 63, wid = threadIdx.x >> 6;
  int m = lane & 15, q = lane >> 4;
  for (int fi = wid; fi < 8; fi += 4) {
    sW1[fi][lane] = zw1f[fi * 64 + lane];
    sW2[fi][lane] = zw2f[fi * 64 + lane];
  }
  if (wid == 0) {
    sWE[0][lane] = walf[lane];
    sWE[1][lane] = walf[64 + lane];
  }
  __syncthreads();
  int ntile = (NT + 15) / 16;
  for (int tile = blockIdx.x * 4 + wid; tile < ntile; tile += nZelBlk * 4) {
    int r0 = tile * 16;
    int row = r0 + m;
    int rowc = (row < NT) ? row : NT - 1;
    int n = rowc / kT;
    float sc = scale[n], sh = shift[n];
    bf16x8 hf[2];
#pragma unroll
    for (int kc = 0; kc < 2; kc++) {
      float4 p0 = *(const float4*)&x[(size_t)rowc * 64 + kc * 32 + q * 8];
      float4 p1 = *(const float4*)&x[(size_t)rowc * 64 + kc * 32 + q * 8 + 4];
      hf[kc][0] = f2bf(fmaf(p0.x, sc, sh));
      hf[kc][1] = f2bf(fmaf(p0.y, sc, sh));
      hf[kc][2] = f2bf(fmaf(p0.z, sc, sh));
      hf[kc][3] = f2bf(fmaf(p0.w, sc, sh));
      hf[kc][4] = f2bf(fmaf(p1.x, sc, sh));
      hf[kc][5] = f2bf(fmaf(p1.y, sc, sh));
      hf[kc][6] = f2bf(fmaf(p1.z, sc, sh));
      hf[kc][7] = f2bf(fmaf(p1.w, sc, sh));
    }
    f32x4 a1[4], a2[4], ae;
#pragma unroll
    for (int mt = 0; mt < 4; mt++) {
      a1[mt] = (f32x4){0.f, 0.f, 0.f, 0.f};
      a2[mt] = (f32x4){0.f, 0.f, 0.f, 0.f};
    }
    ae = (f32x4){0.f, 0.f, 0.f, 0.f};
#pragma unroll
    for (int kc = 0; kc < 2; kc++) {
#pragma unroll
      for (int mt = 0; mt < 4; mt++) {
        a1[mt] = __builtin_amdgcn_mfma_f32_16x16x32_bf16(sW1[mt * 2 + kc][lane], hf[kc],
                                                         a1[mt], 0, 0, 0);
        a2[mt] = __builtin_amdgcn_mfma_f32_16x16x32_bf16(sW2[mt * 2 + kc][lane], hf[kc],
                                                         a2[mt], 0, 0, 0);
      }
      ae = __builtin_amdgcn_mfma_f32_16x16x32_bf16(sWE[kc][lane], hf[kc], ae, 0, 0, 0);
    }
    if (row < NT) {
      // el/er store: quad q selects array; C-layout f=4q+r, col=m=row
      float* edst = (q == 0) ? el1 : (q == 1) ? er1 : (q == 2) ? el2 : er2;
      *(float4*)&edst[(size_t)row * 4] = make_float4(ae[0], ae[1], ae[2], ae[3]);
#pragma unroll
      for (int mt = 0; mt < 4; mt++) {
        uint2 u1 = {pack2(a1[mt][0], a1[mt][1]), pack2(a1[mt][2], a1[mt][3])};
        uint2 u2 = {pack2(a2[mt][0], a2[mt][1]), pack2(a2[mt][2], a2[mt][3])};
        *(uint2*)&z1[(size_t)row * 64 + mt * 16 + 4 * q] = u1;
        *(uint2*)&z2[(size_t)row * 64 + mt * 16 + 4 * q] = u2;
      }
    }
  }
}

// ---------------------------------------------------------------------------
// agg: lane-cooperative edge-id load + depth-3 prefetch pipeline.
// ---------------------------------------------------------------------------
__device__ __forceinline__ void gat_rel(int n, int t, const int* __restrict__ scsr,
                                        const int* __restrict__ off,
                                        const float* __restrict__ elp, float er_h,
                                        const unsigned short* __restrict__ zp, int lane,
                                        float& a0, float& a1, float& a2, float& a3) {
  int b0 = off[n], b1 = off[n + 1];
  if (b1 <= b0) return;
  float den = 0.f, n0 = 0.f, n1 = 0.f, n2 = 0.f, n3 = 0.f;
  for (int c0 = b0; c0 < b1; c0 += 64) {
    int cnt = b1 - c0;
    if (cnt > 64) cnt = 64;
    int idx = c0 + lane;
    int sbl = scsr[(idx < b1) ? idx : b1 - 1];
    int s0 = __shfl(sbl, 0) + t;
    int s1 = (cnt > 1) ? (__shfl(sbl, 1) + t) : s0;
    int s2 = (cnt > 2) ? (__shfl(sbl, 2) + t) : s1;
    float e0 = elp[(size_t)s0 * 4];
    uint2 z0 = *(const uint2*)(zp + (size_t)s0 * 64);
    float e1 = elp[(size_t)s1 * 4];
    uint2 zz1 = *(const uint2*)(zp + (size_t)s1 * 64);
    float e2 = elp[(size_t)s2 * 4];
    uint2 zz2 = *(const uint2*)(zp + (size_t)s2 * 64);
    for (int k = 0; k < cnt; k++) {
      int s3 = (k + 3 < cnt) ? (__shfl(sbl, k + 3) + t) : s2;
      float e3 = elp[(size_t)s3 * 4];
      uint2 zz3 = *(const uint2*)(zp + (size_t)s3 * 64);
      float ev = e0 + er_h;
      ev = fmaxf(ev, kNeg * ev);
      float wgt = exp2f(ev);
      den += wgt;
      n0 = fmaf(wgt, __uint_as_float(z0.x << 16), n0);
      n1 = fmaf(wgt, __uint_as_float(z0.x & 0xffff0000u), n1);
      n2 = fmaf(wgt, __uint_as_float(z0.y << 16), n2);
      n3 = fmaf(wgt, __uint_as_float(z0.y & 0xffff0000u), n3);
      s0 = s1; e0 = e1; z0 = zz1;
      s1 = s2; e1 = e2; zz1 = zz2;
      s2 = s3; e2 = e3; zz2 = zz3;
    }
  }
  float inv = 1.f / den;
  a0 = fmaf(n0, inv, a0);
  a1 = fmaf(n1, inv, a1);
  a2 = fmaf(n2, inv, a2);
  a3 = fmaf(n3, inv, a3);
}

__global__ __launch_bounds__(256) void agg_kernel(
    const float* __restrict__ x, const int* __restrict__ scsr1,
    const int* __restrict__ off1, const float* __restrict__ el1,
    const float* __restrict__ er1, const unsigned short* __restrict__ z1,
    const int* __restrict__ scsr2, const int* __restrict__ off2,
    const float* __restrict__ el2, const float* __restrict__ er2,
    const unsigned short* __restrict__ z2, float* __restrict__ x2,
    float* __restrict__ bn2s, float* __restrict__ bn2q, int N) {
  int wid = threadIdx.x >> 6, lane = threadIdx.x & 63;
  int w = blockIdx.x * 4 + wid;
  if (w >= N * 3) return;
  int n = w / 3;
  int t0 = (w - n * 3) * 4;
  int tl = lane >> 4, cg = lane & 15;
  int t = t0 + tl;
  int row = n * kT + t;
  int h = cg >> 2;
  float a0 = 0.f, a1 = 0.f, a2 = 0.f, a3 = 0.f;
  gat_rel(n, t, scsr1, off1, el1 + h, er1[(size_t)row * 4 + h], z1 + cg * 4, lane, a0, a1, a2,
          a3);
  gat_rel(n, t, scsr2, off2, el2 + h, er2[(size_t)row * 4 + h], z2 + cg * 4, lane, a0, a1, a2,
          a3);

  size_t base = (size_t)row * 64 + cg * 4;
  float4 xr = *(const float4*)&x[base];
  float4 o;
  o.x = xr.x + a0;
  o.y = xr.y + a1;
  o.z = xr.z + a2;
  o.w = xr.w + a3;
  *(float4*)&x2[base] = o;
  float s1 = o.x + o.y + o.z + o.w;
  float s2 = o.x * o.x + o.y * o.y + o.z * o.z + o.w * o.w;
  s1 = wave_reduce_sum(s1);
  s2 = wave_reduce_sum(s2);
  if (lane == 0) {
    atomicAdd(&bn2s[n], s1);
    atomicAdd(&bn2q[n], s2);
  }
}

// ---------------------------------------------------------------------------
// MFMA FF: 2 tiles per wave (2x ILP at same occupancy), BN2 fused, biases in
// LDS, incremental GEMM2. (256,2): no spills (R6 post-mortem).
// ---------------------------------------------------------------------------
__global__ __launch_bounds__(256, 2) void ff_kernel(
    const float* __restrict__ x2, const float* __restrict__ bn2s,
    const float* __restrict__ bn2q, const float* __restrict__ bng,
    const float* __restrict__ bnb, const bf16x8* __restrict__ w1f,
    const bf16x8* __restrict__ w2f, const float* __restrict__ b1,
    const float* __restrict__ b2, float* __restrict__ out, int NT) {
  __shared__ bf16x8 sW1[16][64];
  __shared__ bf16x8 sW2[16][64];
  __shared__ float sB1[128];
  __shared__ float sB2[64];
  int lane = threadIdx.x & 63, wid = threadIdx.x >> 6;
  int m = lane & 15, q = lane >> 4;
  {
    int fi0 = wid * 4;
#pragma unroll
    for (int k = 0; k < 4; k++) {
      sW1[fi0 + k][lane] = w1f[(fi0 + k) * 64 + lane];
      sW2[fi0 + k][lane] = w2f[(fi0 + k) * 64 + lane];
    }
    if (threadIdx.x < 128) sB1[threadIdx.x] = b1[threadIdx.x];
    if (threadIdx.x < 64) sB2[threadIdx.x] = b2[threadIdx.x];
  }
  __syncthreads();

  const float inv = 1.f / 768.f;
  int grp = blockIdx.x * 4 + wid;
  int ngrp = (NT + 31) / 32;
  if (grp >= ngrp) return;

  bf16x8 hf[2][2];
  f32x4 acc[2][8];
#pragma unroll
  for (int tt = 0; tt < 2; tt++) {
    int row = grp * 32 + tt * 16 + m;
    int rowc = (row < NT) ? row : NT - 1;
    int n = rowc / kT;
    float mean = bn2s[n] * inv;
    float var = bn2q[n] * inv - mean * mean;
    float sc = rsqrtf(var + kEps) * bng[n];
    float sh = bnb[n] - mean * sc;
#pragma unroll
    for (int kc = 0; kc < 2; kc++) {
      const float4 p0 = *(const float4*)&x2[(size_t)rowc * 64 + kc * 32 + q * 8];
      const float4 p1 = *(const float4*)&x2[(size_t)rowc * 64 + kc * 32 + q * 8 + 4];
      hf[tt][kc][0] = f2bf(fmaf(p0.x, sc, sh));
      hf[tt][kc][1] = f2bf(fmaf(p0.y, sc, sh));
      hf[tt][kc][2] = f2bf(fmaf(p0.z, sc, sh));
      hf[tt][kc][3] = f2bf(fmaf(p0.w, sc, sh));
      hf[tt][kc][4] = f2bf(fmaf(p1.x, sc, sh));
      hf[tt][kc][5] = f2bf(fmaf(p1.y, sc, sh));
      hf[tt][kc][6] = f2bf(fmaf(p1.z, sc, sh));
      hf[tt][kc][7] = f2bf(fmaf(p1.w, sc, sh));
    }
#pragma unroll
    for (int mt = 0; mt < 8; mt++) acc[tt][mt] = (f32x4){0.f, 0.f, 0.f, 0.f};
  }
#pragma unroll
  for (int kc = 0; kc < 2; kc++)
#pragma unroll
    for (int mt = 0; mt < 8; mt++)
#pragma unroll
      for (int tt = 0; tt < 2; tt++)
        acc[tt][mt] = __builtin_amdgcn_mfma_f32_16x16x32_bf16(sW1[mt * 2 + kc][lane],
                                                              hf[tt][kc], acc[tt][mt], 0, 0, 0);

  f32x4 acc2[2][4];
#pragma unroll
  for (int tt = 0; tt < 2; tt++)
#pragma unroll
    for (int mt = 0; mt < 4; mt++) acc2[tt][mt] = (f32x4){0.f, 0.f, 0.f, 0.f};
#pragma unroll
  for (int kc = 0; kc < 4; kc++) {
    float4 bb0 = *(const float4*)&sB1[(2 * kc) * 16 + 4 * q];
    float4 bb1 = *(const float4*)&sB1[(2 * kc + 1) * 16 + 4 * q];
    bf16x8 bf[2];
#pragma unroll
    for (int tt = 0; tt < 2; tt++) {
      float g0[4], g1[4];
      float u;
      u = acc[tt][2 * kc][0] + bb0.x; g0[0] = 0.5f * u * (1.f + erff(u * 0.70710678118654752f));
      u = acc[tt][2 * kc][1] + bb0.y; g0[1] = 0.5f * u * (1.f + erff(u * 0.70710678118654752f));
      u = acc[tt][2 * kc][2] + bb0.z; g0[2] = 0.5f * u * (1.f + erff(u * 0.70710678118654752f));
      u = acc[tt][2 * kc][3] + bb0.w; g0[3] = 0.5f * u * (1.f + erff(u * 0.70710678118654752f));
      u = acc[tt][2 * kc + 1][0] + bb1.x; g1[0] = 0.5f * u * (1.f + erff(u * 0.70710678118654752f));
      u = acc[tt][2 * kc + 1][1] + bb1.y; g1[1] = 0.5f * u * (1.f + erff(u * 0.70710678118654752f));
      u = acc[tt][2 * kc + 1][2] + bb1.z; g1[2] = 0.5f * u * (1.f + erff(u * 0.70710678118654752f));
      u = acc[tt][2 * kc + 1][3] + bb1.w; g1[3] = 0.5f * u * (1.f + erff(u * 0.70710678118654752f));
#pragma unroll
      for (int j = 0; j < 8; j++) {
        int srcq = (2 * q + (j >> 2)) & 3;
        int src = srcq * 16 + m;
        float v0 = __shfl(g0[j & 3], src);
        float v1 = __shfl(g1[j & 3], src);
        bf[tt][j] = f2bf((q >= 2) ? v1 : v0);
      }
    }
#pragma unroll
    for (int mt = 0; mt < 4; mt++)
#pragma unroll
      for (int tt = 0; tt < 2; tt++)
        acc2[tt][mt] = __builtin_amdgcn_mfma_f32_16x16x32_bf16(sW2[mt * 4 + kc][lane], bf[tt],
                                                               acc2[tt][mt], 0, 0, 0);
  }

#pragma unroll
  for (int tt = 0; tt < 2; tt++) {
    int row = grp * 32 + tt * 16 + m;
    if (row < NT) {
#pragma unroll
      for (int mt = 0; mt < 4; mt++) {
        size_t base = (size_t)row * 64 + mt * 16 + 4 * q;
        float4 xr = *(const float4*)&x2[base];
        float4 bb = *(const float4*)&sB2[mt * 16 + 4 * q];
        float4 o;
        o.x = acc2[tt][mt][0] + bb.x + xr.x;
        o.y = acc2[tt][mt][1] + bb.y + xr.y;
        o.z = acc2[tt][mt][2] + bb.z + xr.z;
        o.w = acc2[tt][mt][3] + bb.w + xr.w;
        *(float4*)&out[base] = o;
      }
    }
  }
}

extern "C" void kernel_launch(void* const* d_in, const int* in_sizes, int n_in,
                              void* d_out, int out_size, void* d_ws, size_t ws_size,
                              hipStream_t stream) {
  const float* x = (const float*)d_in[0];
  const int* src1 = (const int*)d_in[1];
  const int* dst1 = (const int*)d_in[2];
  const int* src2 = (const int*)d_in[3];
  const int* dst2 = (const int*)d_in[4];
  const float* W1 = (const float*)d_in[5];
  const float* al1 = (const float*)d_in[6];
  const float* ar1 = (const float*)d_in[7];
  const float* W2 = (const float*)d_in[8];
  const float* al2 = (const float*)d_in[9];
  const float* ar2 = (const float*)d_in[10];
  const float* g1 = (const float*)d_in[11];
  const float* b1 = (const float*)d_in[12];
  const float* g2 = (const float*)d_in[13];
  const float* b2 = (const float*)d_in[14];
  const float* fw1 = (const float*)d_in[15];
  const float* fb1 = (const float*)d_in[16];
  const float* fw2 = (const float*)d_in[17];
  const float* fb2 = (const float*)d_in[18];

  const int N = in_sizes[11];
  const int E1 = in_sizes[1];
  const int E2 = in_sizes[3];
  const int NT = N * kT;

  char* p = (char*)d_ws;
  auto alloc = [&](size_t bytes) -> char* {
    char* r = p;
    p += (bytes + 255) & ~(size_t)255;
    return r;
  };
  unsigned short* z1 = (unsigned short*)alloc((size_t)NT * 64 * 2);
  unsigned short* z2 = (unsigned short*)alloc((size_t)NT * 64 * 2);
  float* el1 = (float*)alloc((size_t)NT * 4 * 4);
  float* er1 = (float*)alloc((size_t)NT * 4 * 4);
  float* el2 = (float*)alloc((size_t)NT * 4 * 4);
  float* er2 = (float*)alloc((size_t)NT * 4 * 4);
  float* x2 = (float*)alloc((size_t)NT * 64 * 4);
  float* sc1 = (float*)alloc((size_t)N * 4);
  float* sh1 = (float*)alloc((size_t)N * 4);
  int* off1 = (int*)alloc((size_t)(N + 1) * 4);
  int* off2 = (int*)alloc((size_t)(N + 1) * 4);
  int* scsr1 = (int*)alloc((size_t)E1 * 4);
  int* scsr2 = (int*)alloc((size_t)E2 * 4);
  bf16x8* fw1f = (bf16x8*)alloc(16 * 64 * 16);
  bf16x8* fw2f = (bf16x8*)alloc(16 * 64 * 16);
  bf16x8* zw1f = (bf16x8*)alloc(8 * 64 * 16);
  bf16x8* zw2f = (bf16x8*)alloc(8 * 64 * 16);
  bf16x8* walf = (bf16x8*)alloc(2 * 64 * 16);
  char* zero_base = p;
  int* deg1 = (int*)alloc((size_t)N * 4);
  int* cur1 = (int*)alloc((size_t)N * 4);
  int* deg2 = (int*)alloc((size_t)N * 4);
  int* cur2 = (int*)alloc((size_t)N * 4);
  float* bn2s = (float*)alloc((size_t)N * 4);
  float* bn2q = (float*)alloc((size_t)N * 4);
  size_t zero_bytes = (size_t)(p - zero_base);
  hipMemsetAsync(zero_base, 0, zero_bytes, stream);

  const int nBnBlk = (N + 3) / 4;
  const int degBlk = (E1 + E2 + 255) / 256;
  prep_kernel<<<nBnBlk + 4 + degBlk, 256, 0, stream>>>(
      x, g1, b1, sc1, sh1, fw1, fw2, W1, W2, al1, ar1, al2, ar2, fw1f, fw2f, zw1f, zw2f, walf,
      dst1, dst2, deg1, deg2, N, E1, E2, nBnBlk);
  scan_kernel<<<2, 1024, 0, stream>>>(deg1, off1, deg2, off2, N);
  const int nZelBlk = 1875;
  fillzel_kernel<<<nZelBlk + degBlk, 256, 0, stream>>>(
      src1, dst1, off1, cur1, scsr1, src2, dst2, off2, cur2, scsr2, E1, E2, nZelBlk, x, sc1,
      sh1, zw1f, zw2f, walf, z1, z2, el1, er1, el2, er2, NT);
  agg_kernel<<<(N * 3 + 3) / 4, 256, 0, stream>>>(x, scsr1, off1, el1, er1, z1, scsr2, off2,
                                                  el2, er2, z2, x2, bn2s, bn2q, N);
  ff_kernel<<<((NT + 31) / 32 + 3) / 4, 256, 0, stream>>>(x2, bn2s, bn2q, g2, b2, fw1f, fw2f,
                                                          fb1, fb2, (float*)d_out, NT);
}